// Round 3
// baseline (766.276 us; speedup 1.0000x reference)
//
#include <hip/hip_runtime.h>

typedef unsigned short u16;
typedef unsigned int u32;
typedef __attribute__((ext_vector_type(8))) short bf16x8;
typedef __attribute__((ext_vector_type(4))) float f32x4;

#define HW 65536

__device__ __forceinline__ float bf2f(u32 v) { return __uint_as_float(v << 16); }
__device__ __forceinline__ u16 f2bf(float f) {
  u32 u = __float_as_uint(f);
  u += 0x7fffu + ((u >> 16) & 1u);   // RNE; inputs are finite
  return (u16)(u >> 16);
}

// packed bf16 dot2: d = a.l*b.l + a.h*b.h + d  (CDNA VOP3P v_dot2_f32_bf16)
__device__ __forceinline__ float dot2bf(u32 a, u32 b, float d) {
  asm("v_dot2_f32_bf16 %0, %1, %2, %0" : "+v"(d) : "v"(a), "v"(b));
  return d;
}

__device__ __forceinline__ void unpack8(uint4 u, float r[8]) {
  r[0] = bf2f(u.x & 0xffffu); r[1] = bf2f(u.x >> 16);
  r[2] = bf2f(u.y & 0xffffu); r[3] = bf2f(u.y >> 16);
  r[4] = bf2f(u.z & 0xffffu); r[5] = bf2f(u.z >> 16);
  r[6] = bf2f(u.w & 0xffffu); r[7] = bf2f(u.w >> 16);
}

// ---------------- LayerNorm over channel dim (thread = 2 adjacent pixels) ----
template <int INF32>
__global__ __launch_bounds__(256)
void ln_k(const void* __restrict__ xv, const float* __restrict__ gw,
          const float* __restrict__ gb, u16* __restrict__ y, int C)
{
  int pi = blockIdx.x * 256 + threadIdx.x;
  int p2 = pi << 1;
  int b = p2 >> 16;
  int p = p2 & (HW - 1);
  const float* xf = (const float*)xv + (size_t)b * C * HW + p;
  const u16* xh = (const u16*)xv + (size_t)b * C * HW + p;
  u16* yb = y + (size_t)b * C * HW + p;
  float s0 = 0, s1 = 0, q0 = 0, q1 = 0;
  for (int c = 0; c < C; ++c) {
    float a, d;
    if (INF32) {
      float2 u = *(const float2*)(xf + (size_t)c * HW);
      a = u.x; d = u.y;
    } else {
      u32 u = *(const u32*)(xh + (size_t)c * HW);
      a = bf2f(u & 0xffffu); d = bf2f(u >> 16);
    }
    s0 += a; q0 += a * a; s1 += d; q1 += d * d;
  }
  float inv = 1.0f / (float)C;
  float m0 = s0 * inv, m1 = s1 * inv;
  float r0 = rsqrtf(fmaxf(q0 * inv - m0 * m0, 0.f) + 1e-6f);
  float r1 = rsqrtf(fmaxf(q1 * inv - m1 * m1, 0.f) + 1e-6f);
  for (int c = 0; c < C; ++c) {
    float a, d;
    if (INF32) {
      float2 u = *(const float2*)(xf + (size_t)c * HW);
      a = u.x; d = u.y;
    } else {
      u32 u = *(const u32*)(xh + (size_t)c * HW);
      a = bf2f(u & 0xffffu); d = bf2f(u >> 16);
    }
    float w = gw[c], bb = gb[c];
    a = (a - m0) * r0 * w + bb;
    d = (d - m1) * r1 * w + bb;
    *(u32*)(yb + (size_t)c * HW) = (u32)f2bf(a) | ((u32)f2bf(d) << 16);
  }
}

// ---------------- LN2 over 256 channels fused with v-multiply ---------------
__global__ __launch_bounds__(256)
void ln2v_k(u16* __restrict__ qkv, const float* __restrict__ gw,
            const float* __restrict__ gb)
{
  int pi = blockIdx.x * 256 + threadIdx.x;
  int p2 = pi << 1;
  int b = p2 >> 16;
  int p = p2 & (HW - 1);
  u16* ab = qkv + ((size_t)(b * 768) << 16) + p;               // attn (q-slot)
  const u16* vb = qkv + ((size_t)(b * 768 + 512) << 16) + p;   // v
  float s0 = 0, s1 = 0, q0 = 0, q1 = 0;
  for (int c = 0; c < 256; ++c) {
    u32 u = *(const u32*)(ab + (size_t)c * HW);
    float a = bf2f(u & 0xffffu), d = bf2f(u >> 16);
    s0 += a; q0 += a * a; s1 += d; q1 += d * d;
  }
  const float inv = 1.0f / 256.0f;
  float m0 = s0 * inv, m1 = s1 * inv;
  float r0 = rsqrtf(fmaxf(q0 * inv - m0 * m0, 0.f) + 1e-6f);
  float r1 = rsqrtf(fmaxf(q1 * inv - m1 * m1, 0.f) + 1e-6f);
  for (int c = 0; c < 256; ++c) {
    u32 u = *(const u32*)(ab + (size_t)c * HW);
    u32 vv = *(const u32*)(vb + (size_t)c * HW);
    float w = gw[c], bb = gb[c];
    float a = ((bf2f(u & 0xffffu) - m0) * r0 * w + bb) * bf2f(vv & 0xffffu);
    float d = ((bf2f(u >> 16) - m1) * r1 * w + bb) * bf2f(vv >> 16);
    *(u32*)(ab + (size_t)c * HW) = (u32)f2bf(a) | ((u32)f2bf(d) << 16);
  }
}

// ---- B-tile gather helper: u32 = 2 adjacent pixels, 8 channels -> 2 uint4 --
__device__ __forceinline__ void gatherB(const u16* __restrict__ src,
                                        uint4& e, uint4& o)
{
  u32 w0 = *(const u32*)(src);
  u32 w1 = *(const u32*)(src + HW);
  u32 w2 = *(const u32*)(src + 2 * HW);
  u32 w3 = *(const u32*)(src + 3 * HW);
  u32 w4 = *(const u32*)(src + 4 * HW);
  u32 w5 = *(const u32*)(src + 5 * HW);
  u32 w6 = *(const u32*)(src + 6 * HW);
  u32 w7 = *(const u32*)(src + 7 * HW);
  e.x = (w0 & 0xffffu) | (w1 << 16);
  e.y = (w2 & 0xffffu) | (w3 << 16);
  e.z = (w4 & 0xffffu) | (w5 << 16);
  e.w = (w6 & 0xffffu) | (w7 << 16);
  o.x = (w0 >> 16) | (w1 & 0xffff0000u);
  o.y = (w2 >> 16) | (w3 & 0xffff0000u);
  o.z = (w4 >> 16) | (w5 & 0xffff0000u);
  o.w = (w6 >> 16) | (w7 & 0xffff0000u);
}

// ---------------- chunked conv1x1 GEMM (K=256 / single-M cases) -------------
// Epilogue: res[o,p] + acc*scale[o]. AUXF32: residual fp32. OUTF32: Y fp32.
template <int AUXF32, int OUTF32>
__global__ __launch_bounds__(256, 2)
void gemm_k(const float* __restrict__ Wt, const u16* __restrict__ X,
            void* __restrict__ Yv, const void* __restrict__ aux,
            const float* __restrict__ scale, int M, int K, int xbatch)
{
  __shared__ __align__(16) u16 As[4][128][8];   // [kchunk][o][8]
  __shared__ __align__(16) u16 Bs[4][128][8];   // [kchunk][pixel][8]
  int mtiles = M >> 7;
  int mt = blockIdx.x % mtiles;
  int ntile = blockIdx.x / mtiles;
  int n0g = ntile << 7;
  int b = n0g >> 16;
  int p0 = n0g & (HW - 1);
  int o0 = mt << 7;
  const u16* Xb = X + (size_t)b * xbatch * HW;
  int t = threadIdx.x;
  int lane = t & 63, wv = t >> 6;
  int rb = (wv & 1) << 6, cb = (wv >> 1) << 6;
  int qd = lane >> 4, ln = lane & 15;
  f32x4 acc[4][4] = {};
  for (int c0 = 0; c0 < K; c0 += 32) {
#pragma unroll
    for (int it = 0; it < 2; ++it) {
      int tt = t + it * 256;
      int row = tt >> 2, ch = tt & 3;
      const float* wsrc = Wt + (size_t)(o0 + row) * K + c0 + ch * 8;
      uint4 pk;
      pk.x = (u32)f2bf(wsrc[0]) | ((u32)f2bf(wsrc[1]) << 16);
      pk.y = (u32)f2bf(wsrc[2]) | ((u32)f2bf(wsrc[3]) << 16);
      pk.z = (u32)f2bf(wsrc[4]) | ((u32)f2bf(wsrc[5]) << 16);
      pk.w = (u32)f2bf(wsrc[6]) | ((u32)f2bf(wsrc[7]) << 16);
      *(uint4*)&As[ch][row][0] = pk;
    }
    {
      int pp = (t & 63) << 1;
      int kc = t >> 6;
      const u16* src = Xb + (size_t)(c0 + kc * 8) * HW + p0 + pp;
      uint4 e, o;
      gatherB(src, e, o);
      *(uint4*)&Bs[kc][pp][0] = e;
      *(uint4*)&Bs[kc][pp + 1][0] = o;
    }
    __syncthreads();
    bf16x8 af[4], bfv[4];
#pragma unroll
    for (int i = 0; i < 4; ++i) {
      af[i] = *(const bf16x8*)&As[qd][rb + i * 16 + ln][0];
      bfv[i] = *(const bf16x8*)&Bs[qd][cb + i * 16 + ln][0];
    }
#pragma unroll
    for (int i = 0; i < 4; ++i)
#pragma unroll
      for (int j = 0; j < 4; ++j)
        acc[i][j] = __builtin_amdgcn_mfma_f32_16x16x32_bf16(af[i], bfv[j],
                                                            acc[i][j], 0, 0, 0);
    __syncthreads();
  }
  size_t ybase = (size_t)b * M * HW;
#pragma unroll
  for (int i = 0; i < 4; ++i) {
    int obase = o0 + rb + i * 16 + qd * 4;
#pragma unroll
    for (int j = 0; j < 4; ++j) {
      int p = p0 + cb + j * 16 + ln;
#pragma unroll
      for (int rr = 0; rr < 4; ++rr) {
        int o = obase + rr;
        size_t idx = ybase + (size_t)o * HW + p;
        float v = acc[i][j][rr];
        float r = AUXF32 ? ((const float*)aux)[idx]
                         : bf2f((u32)((const u16*)aux)[idx]);
        v = r + v * scale[o];
        if (OUTF32) ((float*)Yv)[idx] = v;
        else        ((u16*)Yv)[idx] = f2bf(v);
      }
    }
  }
}

// ---------------- folded conv1x1 GEMM, K=128: B-tile staged ONCE ------------
template <int EPI>
__global__ __launch_bounds__(256, 2)
void gemmf_k(const float* __restrict__ Wt, const u16* __restrict__ X,
             u16* __restrict__ Y, const float* __restrict__ bias,
             int MT, int xbatch)
{
  __shared__ __align__(16) u16 Bs[16][128][8];   // full-K B tile, 32 KB
  __shared__ __align__(16) u16 As[16][128][8];   // full-K A tile, 32 KB
  int n0g = blockIdx.x << 7;
  int b = n0g >> 16;
  int p0 = n0g & (HW - 1);
  const u16* Xb = X + (size_t)b * xbatch * HW;
  int t = threadIdx.x;
  int lane = t & 63, wv = t >> 6;
  int rb = (wv & 1) << 6, cb = (wv >> 1) << 6;
  int qd = lane >> 4, ln = lane & 15;
#pragma unroll
  for (int it = 0; it < 4; ++it) {
    int tt = t + it * 256;
    int pp = (tt & 63) << 1;
    int kc = tt >> 6;
    const u16* src = Xb + (size_t)(kc * 8) * HW + p0 + pp;
    uint4 e, o;
    gatherB(src, e, o);
    *(uint4*)&Bs[kc][pp][0] = e;
    *(uint4*)&Bs[kc][pp + 1][0] = o;
  }
  int M = MT << 7;
  size_t ybase = (size_t)b * M * HW;
  for (int mt = 0; mt < MT; ++mt) {
    int o0 = mt << 7;
    __syncthreads();   // prior tile's MFMA reads done (mt=0: B writes done)
#pragma unroll
    for (int it = 0; it < 8; ++it) {
      int tt = t + it * 256;
      int row = tt & 127, kc = tt >> 7;
      const float* wsrc = Wt + (size_t)(o0 + row) * 128 + kc * 8;
      float4 w0 = *(const float4*)wsrc;
      float4 w1 = *(const float4*)(wsrc + 4);
      uint4 pk;
      pk.x = (u32)f2bf(w0.x) | ((u32)f2bf(w0.y) << 16);
      pk.y = (u32)f2bf(w0.z) | ((u32)f2bf(w0.w) << 16);
      pk.z = (u32)f2bf(w1.x) | ((u32)f2bf(w1.y) << 16);
      pk.w = (u32)f2bf(w1.z) | ((u32)f2bf(w1.w) << 16);
      *(uint4*)&As[kc][row][0] = pk;
    }
    __syncthreads();
    f32x4 acc[4][4] = {};
#pragma unroll
    for (int s = 0; s < 4; ++s) {
      bf16x8 af[4], bfv[4];
#pragma unroll
      for (int i = 0; i < 4; ++i) {
        af[i] = *(const bf16x8*)&As[s * 4 + qd][rb + i * 16 + ln][0];
        bfv[i] = *(const bf16x8*)&Bs[s * 4 + qd][cb + i * 16 + ln][0];
      }
#pragma unroll
      for (int i = 0; i < 4; ++i)
#pragma unroll
        for (int j = 0; j < 4; ++j)
          acc[i][j] = __builtin_amdgcn_mfma_f32_16x16x32_bf16(af[i], bfv[j],
                                                              acc[i][j], 0, 0, 0);
    }
#pragma unroll
    for (int i = 0; i < 4; ++i) {
      int obase = o0 + rb + i * 16 + qd * 4;
#pragma unroll
      for (int j = 0; j < 4; ++j) {
        int p = p0 + cb + j * 16 + ln;
#pragma unroll
        for (int rr = 0; rr < 4; ++rr) {
          int o = obase + rr;
          float v = acc[i][j][rr];
          if (EPI == 1) v += bias[o];
          Y[ybase + (size_t)o * HW + p] = f2bf(v);
        }
      }
    }
  }
}

// ---------------- depthwise 3x3, SAME zero pad, IN-PLACE (bf16 data) --------
// v3: persistent 256 blocks (1/CU), software-pipelined (T14 async-STAGE):
// per half-channel phase: issue next phase's global loads into regs ->
// compute current half from LDS + in-place global store -> ds_write staged
// regs into the other buffer -> barrier. buf0=rows 0..127, buf1=rows 128..255,
// halo=pristine rows 126,127 copied during phase A (so buf0 can be restaged
// with the next channel while phase B still needs rows 126/127).
// In-place safety: staged reads are always a disjoint channel-half from the
// rows being written; intra-block hazards fenced by the one barrier/phase.
__device__ __forceinline__ void ldrowP(const u16* __restrict__ rp, int w0,
                                       float* r) {
  if (rp == nullptr) {
#pragma unroll
    for (int i = 0; i < 10; ++i) r[i] = 0.f;
    return;
  }
  const u16* p = rp + w0;
  float c[8];
  unpack8(*(const uint4*)p, c);
#pragma unroll
  for (int i = 0; i < 8; ++i) r[i + 1] = c[i];
  r[0] = (w0 > 0) ? bf2f((u32)p[-1]) : 0.f;
  r[9] = (w0 < 248) ? bf2f((u32)p[8]) : 0.f;
}

__device__ __forceinline__ void conv8(const float r0[10], const float r1[10],
                                      const float r2[10], const float wg[9],
                                      uint4& pk) {
  float o[8];
#pragma unroll
  for (int j = 0; j < 8; ++j) {
    float s = 0.f;
#pragma unroll
    for (int dx = 0; dx < 3; ++dx)
      s += r0[j + dx] * wg[dx] + r1[j + dx] * wg[3 + dx] +
           r2[j + dx] * wg[6 + dx];
    o[j] = s;
  }
  pk.x = (u32)f2bf(o[0]) | ((u32)f2bf(o[1]) << 16);
  pk.y = (u32)f2bf(o[2]) | ((u32)f2bf(o[3]) << 16);
  pk.z = (u32)f2bf(o[4]) | ((u32)f2bf(o[5]) << 16);
  pk.w = (u32)f2bf(o[6]) | ((u32)f2bf(o[7]) << 16);
}

__global__ __launch_bounds__(1024)
void dwip_k(u16* __restrict__ buf, const float* __restrict__ wt, int C)
{
  __shared__ __align__(16) uint4 sb0[4096];   // rows 0..127   (64 KB)
  __shared__ __align__(16) uint4 sb1[4096];   // rows 128..255 (64 KB)
  __shared__ __align__(16) uint4 shl[64];     // rows 126,127  (1 KB)
  const u16* B0 = (const u16*)sb0;
  const u16* B1 = (const u16*)sb1;
  const u16* H  = (const u16*)shl;
  int t = threadIdx.x;
  int bx = blockIdx.x;                 // 256 persistent blocks
  uint4* G = (uint4*)buf;              // channel ch = G[ch*8192 .. +8192)
  int nch = 2 * C;                     // 1536 channels (b x C)
  int kmax = nch >> 8;                 // 6 channels per block
  // ---- prologue: stage (ch=bx, rows 0..127) -> buf0
  {
    size_t g0 = (size_t)bx * 8192;
#pragma unroll
    for (int r = 0; r < 4; ++r)
      sb0[t + r * 1024] = G[g0 + t + r * 1024];
  }
  __syncthreads();
  for (int k = 0; k < kmax; ++k) {
    int ch = bx + (k << 8);
    int c = ch % C;
    float wg[9];
#pragma unroll
    for (int i = 0; i < 9; ++i) wg[i] = wt[c * 9 + i];
    uint4* Gch = G + (size_t)ch * 8192;
    // ================= phase A: compute output rows 0..126 =================
    uint4 st[4];
    {
      // stage NEXT = (ch, rows 128..255) -> regs (lands during compute)
      size_t g1 = (size_t)ch * 8192 + 4096;
#pragma unroll
      for (int r = 0; r < 4; ++r)
        st[r] = G[g1 + t + r * 1024];
    }
    if (t < 64) shl[t] = sb0[126 * 32 + t];   // pristine rows 126,127 -> halo
    for (int s = t; s < 4064; s += 1024) {
      int R = s >> 5;                  // 0..126
      int w0 = (s & 31) << 3;
      float r0[10], r1[10], r2[10];
      ldrowP((R == 0) ? nullptr : B0 + ((R - 1) << 8), w0, r0);
      ldrowP(B0 + (R << 8), w0, r1);
      ldrowP(B0 + ((R + 1) << 8), w0, r2);
      uint4 pk;
      conv8(r0, r1, r2, wg, pk);
      Gch[s] = pk;                     // output rows 0..126
    }
#pragma unroll
    for (int r = 0; r < 4; ++r)
      sb1[t + r * 1024] = st[r];       // (compiler waits vmcnt here)
    __syncthreads();
    // ================= phase B: compute output rows 127..255 ===============
    bool hasnext = (k + 1 < kmax);
    if (hasnext) {
      // stage NEXT = (ch+256, rows 0..127) -> regs
      size_t g0 = (size_t)(ch + 256) * 8192;
#pragma unroll
      for (int r = 0; r < 4; ++r)
        st[r] = G[g0 + t + r * 1024];
    }
    for (int s = t; s < 4128; s += 1024) {
      int R = 127 + (s >> 5);          // 127..255
      int w0 = (s & 31) << 3;
      const u16* rm = (R == 127) ? H : (R == 128) ? H + 256
                                                  : B1 + ((R - 129) << 8);
      const u16* rc = (R == 127) ? H + 256 : B1 + ((R - 128) << 8);
      const u16* rp = (R == 255) ? nullptr : B1 + ((R - 127) << 8);
      float r0[10], r1[10], r2[10];
      ldrowP(rm, w0, r0);
      ldrowP(rc, w0, r1);
      ldrowP(rp, w0, r2);
      uint4 pk;
      conv8(r0, r1, r2, wg, pk);
      Gch[4064 + s] = pk;              // output rows 127..255
    }
    if (hasnext) {
#pragma unroll
      for (int r = 0; r < 4; ++r)
        sb0[t + r * 1024] = st[r];
    }
    __syncthreads();
  }
}

// ---------------- fused depthwise-3x3 + gate product (FFN tail) -------------
// block = (b, c in [0,128), half). Stage ch c half-channel (+halo rows) into
// 66.5 KB LDS, conv -> 32 regs; restage ch c+128, conv, multiply, store
// product to pr. NOT in-place, so half-channel tiling is race-free.
__device__ __forceinline__ void ldsrow2(const u16* __restrict__ img, int lr,
                                        int w0, float* r) {
  const u16* rp = img + (lr << 8) + w0;
  float c[8];
  unpack8(*(const uint4*)rp, c);
#pragma unroll
  for (int i = 0; i < 8; ++i) r[i + 1] = c[i];
  r[0] = (w0 > 0) ? bf2f((u32)rp[-1]) : 0.f;
  r[9] = (w0 < 248) ? bf2f((u32)rp[8]) : 0.f;
}

__global__ __launch_bounds__(1024)
void dwfuse_k(const u16* __restrict__ h4, const float* __restrict__ wt,
              u16* __restrict__ pr)
{
  __shared__ __align__(16) u16 img[33280];   // 130 rows x 256, 66.5 KB
  int bx = blockIdx.x;
  int b = bx >> 8;
  int c = (bx >> 1) & 127;
  int half = bx & 1;
  int h0 = half << 7;
  int t = threadIdx.x;
  float o1[32];
  size_t obase = ((size_t)((b << 7) + c) << 16);
#pragma unroll
  for (int pass = 0; pass < 2; ++pass) {
    int ch = c + pass * 128;
    size_t gbase = (size_t)((b << 8) + ch) << 16;
    __syncthreads();             // prior pass conv reads complete
    for (int idx = t; idx < 4160; idx += 1024) {
      int lr = idx >> 5, col = idx & 31;
      int gh = h0 - 1 + lr;
      uint4 v = {0, 0, 0, 0};
      if ((unsigned)gh < 256u)
        v = *(const uint4*)(h4 + gbase + ((size_t)gh << 8) + col * 8);
      *(uint4*)&img[(lr << 8) + col * 8] = v;
    }
    float wg[9];
#pragma unroll
    for (int i = 0; i < 9; ++i) wg[i] = wt[ch * 9 + i];
    __syncthreads();
#pragma unroll
    for (int it = 0; it < 4; ++it) {
      int f = it * 1024 + t;
      int lrr = f >> 5;            // 0..127 output row within half
      int w0 = (f & 31) << 3;
      float r0[10], r1[10], r2[10];
      ldsrow2(img, lrr,     w0, r0);  // global row h0+lrr-1
      ldsrow2(img, lrr + 1, w0, r1);
      ldsrow2(img, lrr + 2, w0, r2);
      float o[8];
#pragma unroll
      for (int j = 0; j < 8; ++j) {
        float s = 0.f;
#pragma unroll
        for (int dx = 0; dx < 3; ++dx)
          s += r0[j + dx] * wg[dx] + r1[j + dx] * wg[3 + dx] +
               r2[j + dx] * wg[6 + dx];
        o[j] = s;
      }
      if (pass == 0) {
#pragma unroll
        for (int j = 0; j < 8; ++j) o1[it * 8 + j] = o[j];
      } else {
        uint4 pk;
        pk.x = (u32)f2bf(o1[it*8+0] * o[0]) | ((u32)f2bf(o1[it*8+1] * o[1]) << 16);
        pk.y = (u32)f2bf(o1[it*8+2] * o[2]) | ((u32)f2bf(o1[it*8+3] * o[3]) << 16);
        pk.z = (u32)f2bf(o1[it*8+4] * o[4]) | ((u32)f2bf(o1[it*8+5] * o[5]) << 16);
        pk.w = (u32)f2bf(o1[it*8+6] * o[6]) | ((u32)f2bf(o1[it*8+7] * o[7]) << 16);
        *(uint4*)(pr + obase + ((size_t)(h0 + lrr) << 8) + w0) = pk;
      }
    }
  }
}

// ---------------- patch-FFT attention = 8x8 circular conv per patch/channel -
// v4: packed-bf16 v_dot2_f32_bf16, m-outer. q,k never unpacked: qp[i][t] as
// loaded; pk[r][n]=(k[r][n], k[r][n-1]) built with 1 op each. 2048 dot2 vs
// 4096 fma + ~2k unpack in v3. Live ~110 regs, no launch-bounds min (R4!).
// In-place over q-slot: q fully register-resident before first store.
__global__ __launch_bounds__(256)
void attn_k(u16* __restrict__ qkv)
{
  int wv = threadIdx.x >> 6, lane = threadIdx.x & 63;
  int task = blockIdx.x * 4 + wv;       // 8192 tasks: b(2) x c(256) x strip(16)
  int b = task >> 12;
  int c = (task >> 4) & 255;
  int strip = task & 15;
  int pr = lane >> 5, pw = lane & 31;
  int row = (strip << 4) + (pr << 3);   // patch top row
  size_t qbase = ((size_t)(b * 768 + c) << 16) + ((size_t)row << 8) + pw * 8;
  size_t kbase = qbase + ((size_t)256 << 16);
  u32 qp[8][4];
  u32 ku[8][4];
#pragma unroll
  for (int i = 0; i < 8; ++i) {
    uint4 qv = *(const uint4*)(qkv + qbase + (i << 8));
    uint4 kv = *(const uint4*)(qkv + kbase + (i << 8));
    qp[i][0] = qv.x; qp[i][1] = qv.y; qp[i][2] = qv.z; qp[i][3] = qv.w;
    ku[i][0] = kv.x; ku[i][1] = kv.y; ku[i][2] = kv.z; ku[i][3] = kv.w;
  }
  // pk[r][n] = pack(lo=k[r][n], hi=k[r][(n-1)&7])
  u32 pk[8][8];
#pragma unroll
  for (int r = 0; r < 8; ++r)
#pragma unroll
    for (int n = 0; n < 8; ++n) {
      if (n & 1) {
        u32 x = ku[r][n >> 1];
        pk[r][n] = (x >> 16) | (x << 16);
      } else {
        pk[r][n] = (ku[r][n >> 1] & 0xffffu) |
                   (ku[r][((n + 7) & 7) >> 1] & 0xffff0000u);
      }
    }
#pragma unroll
  for (int m = 0; m < 8; ++m) {
    float a[8] = {};
#pragma unroll
    for (int i = 0; i < 8; ++i) {
      const int r = (m - i) & 7;
#pragma unroll
      for (int t = 0; t < 4; ++t) {
        const u32 q = qp[i][t];
#pragma unroll
        for (int n = 0; n < 8; ++n)
          a[n] = dot2bf(q, pk[r][(n - 2 * t) & 7], a[n]);
      }
    }
    uint4 pko;
    pko.x = (u32)f2bf(a[0]) | ((u32)f2bf(a[1]) << 16);
    pko.y = (u32)f2bf(a[2]) | ((u32)f2bf(a[3]) << 16);
    pko.z = (u32)f2bf(a[4]) | ((u32)f2bf(a[5]) << 16);
    pko.w = (u32)f2bf(a[6]) | ((u32)f2bf(a[7]) << 16);
    *(uint4*)(qkv + qbase + (m << 8)) = pko;
  }
}

extern "C" void kernel_launch(void* const* d_in, const int* in_sizes, int n_in,
                              void* d_out, int out_size, void* d_ws, size_t ws_size,
                              hipStream_t stream)
{
  (void)in_sizes; (void)n_in; (void)out_size; (void)ws_size;
  const float* x    = (const float*)d_in[0];
  const float* n1w  = (const float*)d_in[1];
  const float* n1b  = (const float*)d_in[2];
  const float* wh1  = (const float*)d_in[3];
  const float* wdw1 = (const float*)d_in[4];
  const float* n2w  = (const float*)d_in[5];
  const float* n2b  = (const float*)d_in[6];
  const float* wp1  = (const float*)d_in[7];
  const float* n3w  = (const float*)d_in[8];
  const float* n3b  = (const float*)d_in[9];
  const float* wh2  = (const float*)d_in[10];
  const float* bh2  = (const float*)d_in[11];
  const float* wdw2 = (const float*)d_in[12];
  const float* wp2  = (const float*)d_in[13];
  const float* sc1  = (const float*)d_in[14];
  const float* sc2  = (const float*)d_in[15];
  float* out = (float*)d_out;
  u16* ws = (u16*)d_ws;

  // workspace (u16 elems), peak ~235 MB:
  //   A = ws          : (2,768,HW)  hidden -> qkv -> attn/va
  //                     later: h3 [0,16.7M) | h4 [16.7M,50.3M) | pr [0,16.7M)
  //   B = ws + 100.7M : (2,128,HW)  hln -> xmid (bf16)
  u16* A = ws;
  u16* B = ws + 100663296;
  u16* h3 = A;
  u16* h4 = A + 16777216;
  u16* pr = A;

  ln_k<1><<<256, 256, 0, stream>>>(x, n1w, n1b, B, 128);                     // hln
  gemmf_k<0><<<1024, 256, 0, stream>>>(wh1, B, A, nullptr, 6, 128);          // hidden
  dwip_k<<<256, 1024, 0, stream>>>(A, wdw1, 768);                            // qkv
  attn_k<<<2048, 256, 0, stream>>>(A);                                       // attn -> q-slot
  ln2v_k<<<256, 256, 0, stream>>>(A, n2w, n2b);                              // va -> q-slot
  gemm_k<1,0><<<1024, 256, 0, stream>>>(wp1, A, B, x, sc1, 128, 256, 768);   // xmid -> B
  ln_k<0><<<256, 256, 0, stream>>>(B, n3w, n3b, h3, 128);
  gemmf_k<1><<<1024, 256, 0, stream>>>(wh2, h3, h4, bh2, 2, 128);            // h4
  dwfuse_k<<<512, 1024, 0, stream>>>(h4, wdw2, pr);                          // pr = g1*g2
  gemm_k<0,1><<<1024, 256, 0, stream>>>(wp2, pr, out, B, sc2, 128, 128, 128);
}

// Round 5
// 673.400 us; speedup vs baseline: 1.1379x; 1.1379x over previous
//
#include <hip/hip_runtime.h>

typedef unsigned short u16;
typedef unsigned int u32;
typedef __attribute__((ext_vector_type(8))) short bf16x8;
typedef __attribute__((ext_vector_type(4))) float f32x4;

#define HW 65536

__device__ __forceinline__ float bf2f(u32 v) { return __uint_as_float(v << 16); }
__device__ __forceinline__ u16 f2bf(float f) {
  u32 u = __float_as_uint(f);
  u += 0x7fffu + ((u >> 16) & 1u);   // RNE; inputs are finite
  return (u16)(u >> 16);
}

// packed bf16 dot2: d = a.l*b.l + a.h*b.h + d  (CDNA VOP3P v_dot2_f32_bf16)
__device__ __forceinline__ float dot2bf(u32 a, u32 b, float d) {
  asm("v_dot2_f32_bf16 %0, %1, %2, %0" : "+v"(d) : "v"(a), "v"(b));
  return d;
}

__device__ __forceinline__ void unpack8(uint4 u, float r[8]) {
  r[0] = bf2f(u.x & 0xffffu); r[1] = bf2f(u.x >> 16);
  r[2] = bf2f(u.y & 0xffffu); r[3] = bf2f(u.y >> 16);
  r[4] = bf2f(u.z & 0xffffu); r[5] = bf2f(u.z >> 16);
  r[6] = bf2f(u.w & 0xffffu); r[7] = bf2f(u.w >> 16);
}

// ---------------- LayerNorm over channel dim (thread = 2 adjacent pixels) ----
template <int INF32>
__global__ __launch_bounds__(256)
void ln_k(const void* __restrict__ xv, const float* __restrict__ gw,
          const float* __restrict__ gb, u16* __restrict__ y, int C)
{
  int pi = blockIdx.x * 256 + threadIdx.x;
  int p2 = pi << 1;
  int b = p2 >> 16;
  int p = p2 & (HW - 1);
  const float* xf = (const float*)xv + (size_t)b * C * HW + p;
  const u16* xh = (const u16*)xv + (size_t)b * C * HW + p;
  u16* yb = y + (size_t)b * C * HW + p;
  float s0 = 0, s1 = 0, q0 = 0, q1 = 0;
  for (int c = 0; c < C; ++c) {
    float a, d;
    if (INF32) {
      float2 u = *(const float2*)(xf + (size_t)c * HW);
      a = u.x; d = u.y;
    } else {
      u32 u = *(const u32*)(xh + (size_t)c * HW);
      a = bf2f(u & 0xffffu); d = bf2f(u >> 16);
    }
    s0 += a; q0 += a * a; s1 += d; q1 += d * d;
  }
  float inv = 1.0f / (float)C;
  float m0 = s0 * inv, m1 = s1 * inv;
  float r0 = rsqrtf(fmaxf(q0 * inv - m0 * m0, 0.f) + 1e-6f);
  float r1 = rsqrtf(fmaxf(q1 * inv - m1 * m1, 0.f) + 1e-6f);
  for (int c = 0; c < C; ++c) {
    float a, d;
    if (INF32) {
      float2 u = *(const float2*)(xf + (size_t)c * HW);
      a = u.x; d = u.y;
    } else {
      u32 u = *(const u32*)(xh + (size_t)c * HW);
      a = bf2f(u & 0xffffu); d = bf2f(u >> 16);
    }
    float w = gw[c], bb = gb[c];
    a = (a - m0) * r0 * w + bb;
    d = (d - m1) * r1 * w + bb;
    *(u32*)(yb + (size_t)c * HW) = (u32)f2bf(a) | ((u32)f2bf(d) << 16);
  }
}

// ---- B-tile gather helper: u32 = 2 adjacent pixels, 8 channels -> 2 uint4 --
__device__ __forceinline__ void gatherB(const u16* __restrict__ src,
                                        uint4& e, uint4& o)
{
  u32 w0 = *(const u32*)(src);
  u32 w1 = *(const u32*)(src + HW);
  u32 w2 = *(const u32*)(src + 2 * HW);
  u32 w3 = *(const u32*)(src + 3 * HW);
  u32 w4 = *(const u32*)(src + 4 * HW);
  u32 w5 = *(const u32*)(src + 5 * HW);
  u32 w6 = *(const u32*)(src + 6 * HW);
  u32 w7 = *(const u32*)(src + 7 * HW);
  e.x = (w0 & 0xffffu) | (w1 << 16);
  e.y = (w2 & 0xffffu) | (w3 << 16);
  e.z = (w4 & 0xffffu) | (w5 << 16);
  e.w = (w6 & 0xffffu) | (w7 << 16);
  o.x = (w0 >> 16) | (w1 & 0xffff0000u);
  o.y = (w2 >> 16) | (w3 & 0xffff0000u);
  o.z = (w4 >> 16) | (w5 & 0xffff0000u);
  o.w = (w6 >> 16) | (w7 & 0xffff0000u);
}

// ---------------- chunked conv1x1 GEMM (K=256 / single-M cases) -------------
// Epilogue: res[o,p] + acc*scale[o]. AUXF32: residual fp32. OUTF32: Y fp32.
template <int AUXF32, int OUTF32>
__global__ __launch_bounds__(256, 2)
void gemm_k(const float* __restrict__ Wt, const u16* __restrict__ X,
            void* __restrict__ Yv, const void* __restrict__ aux,
            const float* __restrict__ scale, int M, int K, int xbatch)
{
  __shared__ __align__(16) u16 As[4][128][8];   // [kchunk][o][8]
  __shared__ __align__(16) u16 Bs[4][128][8];   // [kchunk][pixel][8]
  int mtiles = M >> 7;
  int mt = blockIdx.x % mtiles;
  int ntile = blockIdx.x / mtiles;
  int n0g = ntile << 7;
  int b = n0g >> 16;
  int p0 = n0g & (HW - 1);
  int o0 = mt << 7;
  const u16* Xb = X + (size_t)b * xbatch * HW;
  int t = threadIdx.x;
  int lane = t & 63, wv = t >> 6;
  int rb = (wv & 1) << 6, cb = (wv >> 1) << 6;
  int qd = lane >> 4, ln = lane & 15;
  f32x4 acc[4][4] = {};
  for (int c0 = 0; c0 < K; c0 += 32) {
#pragma unroll
    for (int it = 0; it < 2; ++it) {
      int tt = t + it * 256;
      int row = tt >> 2, ch = tt & 3;
      const float* wsrc = Wt + (size_t)(o0 + row) * K + c0 + ch * 8;
      uint4 pk;
      pk.x = (u32)f2bf(wsrc[0]) | ((u32)f2bf(wsrc[1]) << 16);
      pk.y = (u32)f2bf(wsrc[2]) | ((u32)f2bf(wsrc[3]) << 16);
      pk.z = (u32)f2bf(wsrc[4]) | ((u32)f2bf(wsrc[5]) << 16);
      pk.w = (u32)f2bf(wsrc[6]) | ((u32)f2bf(wsrc[7]) << 16);
      *(uint4*)&As[ch][row][0] = pk;
    }
    {
      int pp = (t & 63) << 1;
      int kc = t >> 6;
      const u16* src = Xb + (size_t)(c0 + kc * 8) * HW + p0 + pp;
      uint4 e, o;
      gatherB(src, e, o);
      *(uint4*)&Bs[kc][pp][0] = e;
      *(uint4*)&Bs[kc][pp + 1][0] = o;
    }
    __syncthreads();
    bf16x8 af[4], bfv[4];
#pragma unroll
    for (int i = 0; i < 4; ++i) {
      af[i] = *(const bf16x8*)&As[qd][rb + i * 16 + ln][0];
      bfv[i] = *(const bf16x8*)&Bs[qd][cb + i * 16 + ln][0];
    }
#pragma unroll
    for (int i = 0; i < 4; ++i)
#pragma unroll
      for (int j = 0; j < 4; ++j)
        acc[i][j] = __builtin_amdgcn_mfma_f32_16x16x32_bf16(af[i], bfv[j],
                                                            acc[i][j], 0, 0, 0);
    __syncthreads();
  }
  size_t ybase = (size_t)b * M * HW;
#pragma unroll
  for (int i = 0; i < 4; ++i) {
    int obase = o0 + rb + i * 16 + qd * 4;
#pragma unroll
    for (int j = 0; j < 4; ++j) {
      int p = p0 + cb + j * 16 + ln;
#pragma unroll
      for (int rr = 0; rr < 4; ++rr) {
        int o = obase + rr;
        size_t idx = ybase + (size_t)o * HW + p;
        float v = acc[i][j][rr];
        float r = AUXF32 ? ((const float*)aux)[idx]
                         : bf2f((u32)((const u16*)aux)[idx]);
        v = r + v * scale[o];
        if (OUTF32) ((float*)Yv)[idx] = v;
        else        ((u16*)Yv)[idx] = f2bf(v);
      }
    }
  }
}

// ------- fused LN2(over 256 ch) + v-multiply + conv1x1 GEMM (wp1 path) ------
// Replaces ln2v_k + gemm_k<1,0>. Stages the full 128px x 256ch attn tile in
// LDS once; computes per-pixel LN stats from LDS in EXACTLY ln2v's summation
// order (serial ascending c, f32 adds -> bit-identical results); then the
// K-loop normalizes each 32-ch chunk IN PLACE in LDS (fused with the v
// multiply, v streamed from global) before the MFMA consumes it.
// Saves ~201 MB HBM (attn 2nd read + va write + va read) and one launch.
__global__ __launch_bounds__(256, 2)
void lngemm_k(const float* __restrict__ Wt, const u16* __restrict__ X,
              u16* __restrict__ Y, const float* __restrict__ aux,
              const float* __restrict__ scale, const float* __restrict__ gw,
              const float* __restrict__ gb)
{
  __shared__ __align__(16) u16 At[32][128][8];   // full-K attn tile, 64 KB
  __shared__ __align__(16) u16 As[4][128][8];    // weight chunk, 8 KB
  __shared__ float stm[128], str[128];           // per-pixel mean / rstd
  int n0g = blockIdx.x << 7;
  int b = n0g >> 16;
  int p0 = n0g & (HW - 1);
  const u16* Xb = X + (size_t)b * 768 * HW;
  int t = threadIdx.x;
  int lane = t & 63, wv = t >> 6;
  int rb = (wv & 1) << 6, cb = (wv >> 1) << 6;
  int qd = lane >> 4, ln = lane & 15;
  // ---- stage full attn tile (q-slot, channels 0..255)
#pragma unroll
  for (int it = 0; it < 8; ++it) {
    int kc = (t >> 6) + it * 4;
    int pp = (t & 63) << 1;
    const u16* src = Xb + (size_t)(kc * 8) * HW + p0 + pp;
    uint4 e, o;
    gatherB(src, e, o);
    *(uint4*)&At[kc][pp][0] = e;
    *(uint4*)&At[kc][pp + 1][0] = o;
  }
  __syncthreads();
  // ---- per-pixel LN stats (order matches ln2v_k exactly)
  if (t < 128) {
    float s0 = 0.f, q0 = 0.f;
    for (int cg = 0; cg < 128; ++cg) {
      u32 u = *(const u32*)&At[cg >> 2][t][(cg & 3) << 1];
      float a = bf2f(u & 0xffffu);
      s0 += a; q0 += a * a;
      float d = bf2f(u >> 16);
      s0 += d; q0 += d * d;
    }
    const float inv = 1.0f / 256.0f;
    float m0 = s0 * inv;
    stm[t] = m0;
    str[t] = rsqrtf(fmaxf(q0 * inv - m0 * m0, 0.f) + 1e-6f);
  }
  __syncthreads();
  f32x4 acc[4][4] = {};
  for (int c0 = 0; c0 < 256; c0 += 32) {
    // stage weight chunk (M=128 fixed, K=256 fixed, o0=0)
#pragma unroll
    for (int it = 0; it < 2; ++it) {
      int tt = t + it * 256;
      int row = tt >> 2, chl = tt & 3;
      const float* wsrc = Wt + (size_t)row * 256 + c0 + chl * 8;
      uint4 pk;
      pk.x = (u32)f2bf(wsrc[0]) | ((u32)f2bf(wsrc[1]) << 16);
      pk.y = (u32)f2bf(wsrc[2]) | ((u32)f2bf(wsrc[3]) << 16);
      pk.z = (u32)f2bf(wsrc[4]) | ((u32)f2bf(wsrc[5]) << 16);
      pk.w = (u32)f2bf(wsrc[6]) | ((u32)f2bf(wsrc[7]) << 16);
      *(uint4*)&As[chl][row][0] = pk;
    }
    // normalize this chunk in place, fused with v multiply
    {
      int kcg = (c0 >> 3) + (t >> 6);
      int pp = (t & 63) << 1;
      const u16* vsrc = Xb + (size_t)(512 + kcg * 8) * HW + p0 + pp;
      uint4 ve, vo;
      gatherB(vsrc, ve, vo);
      float w8[8], b8[8];
#pragma unroll
      for (int j = 0; j < 8; ++j) {
        w8[j] = gw[kcg * 8 + j];
        b8[j] = gb[kcg * 8 + j];
      }
      float m0 = stm[pp], r0 = str[pp];
      float m1 = stm[pp + 1], r1 = str[pp + 1];
      uint4 e = *(const uint4*)&At[kcg][pp][0];
      uint4 o = *(const uint4*)&At[kcg][pp + 1][0];
      const u32* ew = (const u32*)&e;
      const u32* ow = (const u32*)&o;
      const u32* vew = (const u32*)&ve;
      const u32* vow = (const u32*)&vo;
      u32 re[4], ro[4];
#pragma unroll
      for (int j = 0; j < 4; ++j) {
        float a0 = ((bf2f(ew[j] & 0xffffu) - m0) * r0 * w8[2 * j] + b8[2 * j]) *
                   bf2f(vew[j] & 0xffffu);
        float a1 = ((bf2f(ew[j] >> 16) - m0) * r0 * w8[2 * j + 1] + b8[2 * j + 1]) *
                   bf2f(vew[j] >> 16);
        re[j] = (u32)f2bf(a0) | ((u32)f2bf(a1) << 16);
        float d0 = ((bf2f(ow[j] & 0xffffu) - m1) * r1 * w8[2 * j] + b8[2 * j]) *
                   bf2f(vow[j] & 0xffffu);
        float d1 = ((bf2f(ow[j] >> 16) - m1) * r1 * w8[2 * j + 1] + b8[2 * j + 1]) *
                   bf2f(vow[j] >> 16);
        ro[j] = (u32)f2bf(d0) | ((u32)f2bf(d1) << 16);
      }
      *(uint4*)&At[kcg][pp][0] = *(const uint4*)re;
      *(uint4*)&At[kcg][pp + 1][0] = *(const uint4*)ro;
    }
    __syncthreads();
    bf16x8 af[4], bfv[4];
    int kb = c0 >> 3;
#pragma unroll
    for (int i = 0; i < 4; ++i) {
      af[i] = *(const bf16x8*)&As[qd][rb + i * 16 + ln][0];
      bfv[i] = *(const bf16x8*)&At[kb + qd][cb + i * 16 + ln][0];
    }
#pragma unroll
    for (int i = 0; i < 4; ++i)
#pragma unroll
      for (int j = 0; j < 4; ++j)
        acc[i][j] = __builtin_amdgcn_mfma_f32_16x16x32_bf16(af[i], bfv[j],
                                                            acc[i][j], 0, 0, 0);
    __syncthreads();
  }
  size_t ybase = (size_t)b * 128 * HW;
#pragma unroll
  for (int i = 0; i < 4; ++i) {
    int obase = rb + i * 16 + qd * 4;
#pragma unroll
    for (int j = 0; j < 4; ++j) {
      int p = p0 + cb + j * 16 + ln;
#pragma unroll
      for (int rr = 0; rr < 4; ++rr) {
        int o = obase + rr;
        size_t idx = ybase + (size_t)o * HW + p;
        float v = acc[i][j][rr];
        float r = aux[idx];
        Y[idx] = f2bf(r + v * scale[o]);
      }
    }
  }
}

// ---------------- folded conv1x1 GEMM, K=128: B-tile staged ONCE ------------
template <int EPI>
__global__ __launch_bounds__(256, 2)
void gemmf_k(const float* __restrict__ Wt, const u16* __restrict__ X,
             u16* __restrict__ Y, const float* __restrict__ bias,
             int MT, int xbatch)
{
  __shared__ __align__(16) u16 Bs[16][128][8];   // full-K B tile, 32 KB
  __shared__ __align__(16) u16 As[16][128][8];   // full-K A tile, 32 KB
  int n0g = blockIdx.x << 7;
  int b = n0g >> 16;
  int p0 = n0g & (HW - 1);
  const u16* Xb = X + (size_t)b * xbatch * HW;
  int t = threadIdx.x;
  int lane = t & 63, wv = t >> 6;
  int rb = (wv & 1) << 6, cb = (wv >> 1) << 6;
  int qd = lane >> 4, ln = lane & 15;
#pragma unroll
  for (int it = 0; it < 4; ++it) {
    int tt = t + it * 256;
    int pp = (tt & 63) << 1;
    int kc = tt >> 6;
    const u16* src = Xb + (size_t)(kc * 8) * HW + p0 + pp;
    uint4 e, o;
    gatherB(src, e, o);
    *(uint4*)&Bs[kc][pp][0] = e;
    *(uint4*)&Bs[kc][pp + 1][0] = o;
  }
  int M = MT << 7;
  size_t ybase = (size_t)b * M * HW;
  for (int mt = 0; mt < MT; ++mt) {
    int o0 = mt << 7;
    __syncthreads();   // prior tile's MFMA reads done (mt=0: B writes done)
#pragma unroll
    for (int it = 0; it < 8; ++it) {
      int tt = t + it * 256;
      int row = tt & 127, kc = tt >> 7;
      const float* wsrc = Wt + (size_t)(o0 + row) * 128 + kc * 8;
      float4 w0 = *(const float4*)wsrc;
      float4 w1 = *(const float4*)(wsrc + 4);
      uint4 pk;
      pk.x = (u32)f2bf(w0.x) | ((u32)f2bf(w0.y) << 16);
      pk.y = (u32)f2bf(w0.z) | ((u32)f2bf(w0.w) << 16);
      pk.z = (u32)f2bf(w1.x) | ((u32)f2bf(w1.y) << 16);
      pk.w = (u32)f2bf(w1.z) | ((u32)f2bf(w1.w) << 16);
      *(uint4*)&As[kc][row][0] = pk;
    }
    __syncthreads();
    f32x4 acc[4][4] = {};
#pragma unroll
    for (int s = 0; s < 4; ++s) {
      bf16x8 af[4], bfv[4];
#pragma unroll
      for (int i = 0; i < 4; ++i) {
        af[i] = *(const bf16x8*)&As[s * 4 + qd][rb + i * 16 + ln][0];
        bfv[i] = *(const bf16x8*)&Bs[s * 4 + qd][cb + i * 16 + ln][0];
      }
#pragma unroll
      for (int i = 0; i < 4; ++i)
#pragma unroll
        for (int j = 0; j < 4; ++j)
          acc[i][j] = __builtin_amdgcn_mfma_f32_16x16x32_bf16(af[i], bfv[j],
                                                              acc[i][j], 0, 0, 0);
    }
#pragma unroll
    for (int i = 0; i < 4; ++i) {
      int obase = o0 + rb + i * 16 + qd * 4;
#pragma unroll
      for (int j = 0; j < 4; ++j) {
        int p = p0 + cb + j * 16 + ln;
#pragma unroll
        for (int rr = 0; rr < 4; ++rr) {
          int o = obase + rr;
          float v = acc[i][j][rr];
          if (EPI == 1) v += bias[o];
          Y[ybase + (size_t)o * HW + p] = f2bf(v);
        }
      }
    }
  }
}

// ---------------- depthwise 3x3, SAME zero pad, IN-PLACE (bf16 data) --------
// v1 (reverted): full 128 KB channel staged per block; 1536 blocks. v2
// (half-LDS, 2 blk/CU) and v3 (persistent reg-pipelined) both regressed:
// v3 blew up HBM traffic (WRITE 197->377 MB: L2 thrash from in-flight
// prefetch + in-place store streams). v1 has exactly-logical traffic.
__device__ __forceinline__ void ldsrow(const u16* __restrict__ img, int h,
                                       int w0, float* r) {
  if ((unsigned)h > 255u) {
#pragma unroll
    for (int i = 0; i < 10; ++i) r[i] = 0.f;
    return;
  }
  const u16* rp = img + (h << 8) + w0;
  float c[8];
  unpack8(*(const uint4*)rp, c);
#pragma unroll
  for (int i = 0; i < 8; ++i) r[i + 1] = c[i];
  r[0] = (w0 > 0) ? bf2f((u32)rp[-1]) : 0.f;
  r[9] = (w0 < 248) ? bf2f((u32)rp[8]) : 0.f;
}

__global__ __launch_bounds__(1024)
void dwip_k(u16* __restrict__ buf, const float* __restrict__ wt, int C)
{
  __shared__ __align__(16) u16 img[65536];   // 128 KB: full channel
  int bc = blockIdx.x;                       // b*C + c
  int c = bc % C;
  size_t base = (size_t)bc << 16;
  int t = threadIdx.x;
  uint4* simg = (uint4*)img;
  const uint4* gsrc = (const uint4*)(buf + base);
#pragma unroll
  for (int it = 0; it < 8; ++it)
    simg[it * 1024 + t] = gsrc[it * 1024 + t];
  float wg[9];
#pragma unroll
  for (int i = 0; i < 9; ++i) wg[i] = wt[c * 9 + i];
  __syncthreads();
  uint4* gdst = (uint4*)(buf + base);
#pragma unroll
  for (int it = 0; it < 8; ++it) {
    int f = it * 1024 + t;
    int h = f >> 5;
    int w0 = (f & 31) << 3;
    float r0[10], r1[10], r2[10];
    ldsrow(img, h - 1, w0, r0);
    ldsrow(img, h,     w0, r1);
    ldsrow(img, h + 1, w0, r2);
    float o[8];
#pragma unroll
    for (int j = 0; j < 8; ++j) {
      float s = 0.f;
#pragma unroll
      for (int dx = 0; dx < 3; ++dx)
        s += r0[j + dx] * wg[dx] + r1[j + dx] * wg[3 + dx] +
             r2[j + dx] * wg[6 + dx];
      o[j] = s;
    }
    uint4 pk;
    pk.x = (u32)f2bf(o[0]) | ((u32)f2bf(o[1]) << 16);
    pk.y = (u32)f2bf(o[2]) | ((u32)f2bf(o[3]) << 16);
    pk.z = (u32)f2bf(o[4]) | ((u32)f2bf(o[5]) << 16);
    pk.w = (u32)f2bf(o[6]) | ((u32)f2bf(o[7]) << 16);
    gdst[f] = pk;   // global write; LDS still holds pristine input
  }
}

// ---------------- fused depthwise-3x3 + gate product (FFN tail) -------------
__device__ __forceinline__ void ldsrow2(const u16* __restrict__ img, int lr,
                                        int w0, float* r) {
  const u16* rp = img + (lr << 8) + w0;
  float c[8];
  unpack8(*(const uint4*)rp, c);
#pragma unroll
  for (int i = 0; i < 8; ++i) r[i + 1] = c[i];
  r[0] = (w0 > 0) ? bf2f((u32)rp[-1]) : 0.f;
  r[9] = (w0 < 248) ? bf2f((u32)rp[8]) : 0.f;
}

__global__ __launch_bounds__(1024)
void dwfuse_k(const u16* __restrict__ h4, const float* __restrict__ wt,
              u16* __restrict__ pr)
{
  __shared__ __align__(16) u16 img[33280];   // 130 rows x 256, 66.5 KB
  int bx = blockIdx.x;
  int b = bx >> 8;
  int c = (bx >> 1) & 127;
  int half = bx & 1;
  int h0 = half << 7;
  int t = threadIdx.x;
  float o1[32];
  size_t obase = ((size_t)((b << 7) + c) << 16);
#pragma unroll
  for (int pass = 0; pass < 2; ++pass) {
    int ch = c + pass * 128;
    size_t gbase = (size_t)((b << 8) + ch) << 16;
    __syncthreads();             // prior pass conv reads complete
    for (int idx = t; idx < 4160; idx += 1024) {
      int lr = idx >> 5, col = idx & 31;
      int gh = h0 - 1 + lr;
      uint4 v = {0, 0, 0, 0};
      if ((unsigned)gh < 256u)
        v = *(const uint4*)(h4 + gbase + ((size_t)gh << 8) + col * 8);
      *(uint4*)&img[(lr << 8) + col * 8] = v;
    }
    float wg[9];
#pragma unroll
    for (int i = 0; i < 9; ++i) wg[i] = wt[ch * 9 + i];
    __syncthreads();
#pragma unroll
    for (int it = 0; it < 4; ++it) {
      int f = it * 1024 + t;
      int lrr = f >> 5;            // 0..127 output row within half
      int w0 = (f & 31) << 3;
      float r0[10], r1[10], r2[10];
      ldsrow2(img, lrr,     w0, r0);  // global row h0+lrr-1
      ldsrow2(img, lrr + 1, w0, r1);
      ldsrow2(img, lrr + 2, w0, r2);
      float o[8];
#pragma unroll
      for (int j = 0; j < 8; ++j) {
        float s = 0.f;
#pragma unroll
        for (int dx = 0; dx < 3; ++dx)
          s += r0[j + dx] * wg[dx] + r1[j + dx] * wg[3 + dx] +
               r2[j + dx] * wg[6 + dx];
        o[j] = s;
      }
      if (pass == 0) {
#pragma unroll
        for (int j = 0; j < 8; ++j) o1[it * 8 + j] = o[j];
      } else {
        uint4 pk;
        pk.x = (u32)f2bf(o1[it*8+0] * o[0]) | ((u32)f2bf(o1[it*8+1] * o[1]) << 16);
        pk.y = (u32)f2bf(o1[it*8+2] * o[2]) | ((u32)f2bf(o1[it*8+3] * o[3]) << 16);
        pk.z = (u32)f2bf(o1[it*8+4] * o[4]) | ((u32)f2bf(o1[it*8+5] * o[5]) << 16);
        pk.w = (u32)f2bf(o1[it*8+6] * o[6]) | ((u32)f2bf(o1[it*8+7] * o[7]) << 16);
        *(uint4*)(pr + obase + ((size_t)(h0 + lrr) << 8) + w0) = pk;
      }
    }
  }
}

// ---------------- patch-FFT attention = 8x8 circular conv per patch/channel -
__global__ __launch_bounds__(256)
void attn_k(u16* __restrict__ qkv)
{
  int wv = threadIdx.x >> 6, lane = threadIdx.x & 63;
  int task = blockIdx.x * 4 + wv;       // 8192 tasks: b(2) x c(256) x strip(16)
  int b = task >> 12;
  int c = (task >> 4) & 255;
  int strip = task & 15;
  int pr = lane >> 5, pw = lane & 31;
  int row = (strip << 4) + (pr << 3);   // patch top row
  size_t qbase = ((size_t)(b * 768 + c) << 16) + ((size_t)row << 8) + pw * 8;
  size_t kbase = qbase + ((size_t)256 << 16);
  u32 qp[8][4];
  u32 ku[8][4];
#pragma unroll
  for (int i = 0; i < 8; ++i) {
    uint4 qv = *(const uint4*)(qkv + qbase + (i << 8));
    uint4 kv = *(const uint4*)(qkv + kbase + (i << 8));
    qp[i][0] = qv.x; qp[i][1] = qv.y; qp[i][2] = qv.z; qp[i][3] = qv.w;
    ku[i][0] = kv.x; ku[i][1] = kv.y; ku[i][2] = kv.z; ku[i][3] = kv.w;
  }
  // pk[r][n] = pack(lo=k[r][n], hi=k[r][(n-1)&7])
  u32 pk[8][8];
#pragma unroll
  for (int r = 0; r < 8; ++r)
#pragma unroll
    for (int n = 0; n < 8; ++n) {
      if (n & 1) {
        u32 x = ku[r][n >> 1];
        pk[r][n] = (x >> 16) | (x << 16);
      } else {
        pk[r][n] = (ku[r][n >> 1] & 0xffffu) |
                   (ku[r][((n + 7) & 7) >> 1] & 0xffff0000u);
      }
    }
#pragma unroll
  for (int m = 0; m < 8; ++m) {
    float a[8] = {};
#pragma unroll
    for (int i = 0; i < 8; ++i) {
      const int r = (m - i) & 7;
#pragma unroll
      for (int t = 0; t < 4; ++t) {
        const u32 q = qp[i][t];
#pragma unroll
        for (int n = 0; n < 8; ++n)
          a[n] = dot2bf(q, pk[r][(n - 2 * t) & 7], a[n]);
      }
    }
    uint4 pko;
    pko.x = (u32)f2bf(a[0]) | ((u32)f2bf(a[1]) << 16);
    pko.y = (u32)f2bf(a[2]) | ((u32)f2bf(a[3]) << 16);
    pko.z = (u32)f2bf(a[4]) | ((u32)f2bf(a[5]) << 16);
    pko.w = (u32)f2bf(a[6]) | ((u32)f2bf(a[7]) << 16);
    *(uint4*)(qkv + qbase + (m << 8)) = pko;
  }
}

extern "C" void kernel_launch(void* const* d_in, const int* in_sizes, int n_in,
                              void* d_out, int out_size, void* d_ws, size_t ws_size,
                              hipStream_t stream)
{
  (void)in_sizes; (void)n_in; (void)out_size; (void)ws_size;
  const float* x    = (const float*)d_in[0];
  const float* n1w  = (const float*)d_in[1];
  const float* n1b  = (const float*)d_in[2];
  const float* wh1  = (const float*)d_in[3];
  const float* wdw1 = (const float*)d_in[4];
  const float* n2w  = (const float*)d_in[5];
  const float* n2b  = (const float*)d_in[6];
  const float* wp1  = (const float*)d_in[7];
  const float* n3w  = (const float*)d_in[8];
  const float* n3b  = (const float*)d_in[9];
  const float* wh2  = (const float*)d_in[10];
  const float* bh2  = (const float*)d_in[11];
  const float* wdw2 = (const float*)d_in[12];
  const float* wp2  = (const float*)d_in[13];
  const float* sc1  = (const float*)d_in[14];
  const float* sc2  = (const float*)d_in[15];
  float* out = (float*)d_out;
  u16* ws = (u16*)d_ws;

  // workspace (u16 elems), peak ~235 MB:
  //   A = ws          : (2,768,HW)  hidden -> qkv -> attn (raw, in q-slot)
  //                     later: h3 [0,16.7M) | h4 [16.7M,50.3M) | pr [0,16.7M)
  //   B = ws + 100.7M : (2,128,HW)  hln -> xmid (bf16)
  u16* A = ws;
  u16* B = ws + 100663296;
  u16* h3 = A;
  u16* h4 = A + 16777216;
  u16* pr = A;

  ln_k<1><<<256, 256, 0, stream>>>(x, n1w, n1b, B, 128);                     // hln
  gemmf_k<0><<<1024, 256, 0, stream>>>(wh1, B, A, nullptr, 6, 128);          // hidden
  dwip_k<<<1536, 1024, 0, stream>>>(A, wdw1, 768);                           // qkv
  attn_k<<<2048, 256, 0, stream>>>(A);                                       // attn -> q-slot
  lngemm_k<<<1024, 256, 0, stream>>>(wp1, A, B, x, sc1, n2w, n2b);           // LN2+v*+wp1 -> B
  ln_k<0><<<256, 256, 0, stream>>>(B, n3w, n3b, h3, 128);
  gemmf_k<1><<<1024, 256, 0, stream>>>(wh2, h3, h4, bh2, 2, 128);            // h4
  dwfuse_k<<<512, 1024, 0, stream>>>(h4, wdw2, pr);                          // pr = g1*g2
  gemm_k<0,1><<<1024, 256, 0, stream>>>(wp2, pr, out, B, sc2, 128, 128, 128);
}

// Round 6
// 622.378 us; speedup vs baseline: 1.2312x; 1.0820x over previous
//
#include <hip/hip_runtime.h>

typedef unsigned short u16;
typedef unsigned int u32;
typedef __attribute__((ext_vector_type(8))) short bf16x8;
typedef __attribute__((ext_vector_type(4))) float f32x4;

#define HW 65536

__device__ __forceinline__ float bf2f(u32 v) { return __uint_as_float(v << 16); }
__device__ __forceinline__ u16 f2bf(float f) {
  u32 u = __float_as_uint(f);
  u += 0x7fffu + ((u >> 16) & 1u);   // RNE; inputs are finite
  return (u16)(u >> 16);
}

// packed bf16 dot2: d = a.l*b.l + a.h*b.h + d  (CDNA VOP3P v_dot2_f32_bf16)
__device__ __forceinline__ float dot2bf(u32 a, u32 b, float d) {
  asm("v_dot2_f32_bf16 %0, %1, %2, %0" : "+v"(d) : "v"(a), "v"(b));
  return d;
}

__device__ __forceinline__ void unpack8(uint4 u, float r[8]) {
  r[0] = bf2f(u.x & 0xffffu); r[1] = bf2f(u.x >> 16);
  r[2] = bf2f(u.y & 0xffffu); r[3] = bf2f(u.y >> 16);
  r[4] = bf2f(u.z & 0xffffu); r[5] = bf2f(u.z >> 16);
  r[6] = bf2f(u.w & 0xffffu); r[7] = bf2f(u.w >> 16);
}

// ---- weight prep: convert wh1/wp1/wh2 to bf16, pre-swizzled into the exact
// LDS As layouts, into d_out scratch (dead until final kernel overwrites all).
//   S0 = S         [98304): wh1 [mt6][kc16][row128][j8]
//   S1 = S + 98304 [32768): wp1 [c0c8][chl4][row128][j8]
//   S2 = S +131072 [32768): wh2 [mt2][kc16][row128][j8]
__global__ __launch_bounds__(256)
void wprep_k(const float* __restrict__ wh1, const float* __restrict__ wp1,
             const float* __restrict__ wh2, u16* __restrict__ S)
{
  int i = blockIdx.x * 256 + threadIdx.x;   // 0..163839
  if (i < 98304) {
    int j = i & 7, row = (i >> 3) & 127, kc = (i >> 10) & 15, mt = i >> 14;
    S[i] = f2bf(wh1[(mt * 128 + row) * 128 + kc * 8 + j]);
  } else if (i < 131072) {
    int k = i - 98304;
    int j = k & 7, row = (k >> 3) & 127, chl = (k >> 10) & 3, c0c = k >> 12;
    S[i] = f2bf(wp1[row * 256 + c0c * 32 + chl * 8 + j]);
  } else if (i < 163840) {
    int k = i - 131072;
    int j = k & 7, row = (k >> 3) & 127, kc = (k >> 10) & 15, mt = k >> 14;
    S[i] = f2bf(wh2[(mt * 128 + row) * 128 + kc * 8 + j]);
  }
}

// ---------------- LayerNorm over channel dim (thread = 2 adjacent pixels) ----
template <int INF32>
__global__ __launch_bounds__(256)
void ln_k(const void* __restrict__ xv, const float* __restrict__ gw,
          const float* __restrict__ gb, u16* __restrict__ y, int C)
{
  int pi = blockIdx.x * 256 + threadIdx.x;
  int p2 = pi << 1;
  int b = p2 >> 16;
  int p = p2 & (HW - 1);
  const float* xf = (const float*)xv + (size_t)b * C * HW + p;
  const u16* xh = (const u16*)xv + (size_t)b * C * HW + p;
  u16* yb = y + (size_t)b * C * HW + p;
  float s0 = 0, s1 = 0, q0 = 0, q1 = 0;
  for (int c = 0; c < C; ++c) {
    float a, d;
    if (INF32) {
      float2 u = *(const float2*)(xf + (size_t)c * HW);
      a = u.x; d = u.y;
    } else {
      u32 u = *(const u32*)(xh + (size_t)c * HW);
      a = bf2f(u & 0xffffu); d = bf2f(u >> 16);
    }
    s0 += a; q0 += a * a; s1 += d; q1 += d * d;
  }
  float inv = 1.0f / (float)C;
  float m0 = s0 * inv, m1 = s1 * inv;
  float r0 = rsqrtf(fmaxf(q0 * inv - m0 * m0, 0.f) + 1e-6f);
  float r1 = rsqrtf(fmaxf(q1 * inv - m1 * m1, 0.f) + 1e-6f);
  for (int c = 0; c < C; ++c) {
    float a, d;
    if (INF32) {
      float2 u = *(const float2*)(xf + (size_t)c * HW);
      a = u.x; d = u.y;
    } else {
      u32 u = *(const u32*)(xh + (size_t)c * HW);
      a = bf2f(u & 0xffffu); d = bf2f(u >> 16);
    }
    float w = gw[c], bb = gb[c];
    a = (a - m0) * r0 * w + bb;
    d = (d - m1) * r1 * w + bb;
    *(u32*)(yb + (size_t)c * HW) = (u32)f2bf(a) | ((u32)f2bf(d) << 16);
  }
}

// ---- B-tile gather helper: u32 = 2 adjacent pixels, 8 channels -> 2 uint4 --
__device__ __forceinline__ void gatherB(const u16* __restrict__ src,
                                        uint4& e, uint4& o)
{
  u32 w0 = *(const u32*)(src);
  u32 w1 = *(const u32*)(src + HW);
  u32 w2 = *(const u32*)(src + 2 * HW);
  u32 w3 = *(const u32*)(src + 3 * HW);
  u32 w4 = *(const u32*)(src + 4 * HW);
  u32 w5 = *(const u32*)(src + 5 * HW);
  u32 w6 = *(const u32*)(src + 6 * HW);
  u32 w7 = *(const u32*)(src + 7 * HW);
  e.x = (w0 & 0xffffu) | (w1 << 16);
  e.y = (w2 & 0xffffu) | (w3 << 16);
  e.z = (w4 & 0xffffu) | (w5 << 16);
  e.w = (w6 & 0xffffu) | (w7 << 16);
  o.x = (w0 >> 16) | (w1 & 0xffff0000u);
  o.y = (w2 >> 16) | (w3 & 0xffff0000u);
  o.z = (w4 >> 16) | (w5 & 0xffff0000u);
  o.w = (w6 >> 16) | (w7 & 0xffff0000u);
}

// ---------------- chunked conv1x1 GEMM (final wp2 case, f32 weights) --------
// Epilogue: res[o,p] + acc*scale[o]. AUXF32: residual fp32. OUTF32: Y fp32.
template <int AUXF32, int OUTF32>
__global__ __launch_bounds__(256, 2)
void gemm_k(const float* __restrict__ Wt, const u16* __restrict__ X,
            void* __restrict__ Yv, const void* __restrict__ aux,
            const float* __restrict__ scale, int M, int K, int xbatch)
{
  __shared__ __align__(16) u16 As[4][128][8];   // [kchunk][o][8]
  __shared__ __align__(16) u16 Bs[4][128][8];   // [kchunk][pixel][8]
  int mtiles = M >> 7;
  int mt = blockIdx.x % mtiles;
  int ntile = blockIdx.x / mtiles;
  int n0g = ntile << 7;
  int b = n0g >> 16;
  int p0 = n0g & (HW - 1);
  int o0 = mt << 7;
  const u16* Xb = X + (size_t)b * xbatch * HW;
  int t = threadIdx.x;
  int lane = t & 63, wv = t >> 6;
  int rb = (wv & 1) << 6, cb = (wv >> 1) << 6;
  int qd = lane >> 4, ln = lane & 15;
  f32x4 acc[4][4] = {};
  for (int c0 = 0; c0 < K; c0 += 32) {
#pragma unroll
    for (int it = 0; it < 2; ++it) {
      int tt = t + it * 256;
      int row = tt >> 2, ch = tt & 3;
      const float* wsrc = Wt + (size_t)(o0 + row) * K + c0 + ch * 8;
      uint4 pk;
      pk.x = (u32)f2bf(wsrc[0]) | ((u32)f2bf(wsrc[1]) << 16);
      pk.y = (u32)f2bf(wsrc[2]) | ((u32)f2bf(wsrc[3]) << 16);
      pk.z = (u32)f2bf(wsrc[4]) | ((u32)f2bf(wsrc[5]) << 16);
      pk.w = (u32)f2bf(wsrc[6]) | ((u32)f2bf(wsrc[7]) << 16);
      *(uint4*)&As[ch][row][0] = pk;
    }
    {
      int pp = (t & 63) << 1;
      int kc = t >> 6;
      const u16* src = Xb + (size_t)(c0 + kc * 8) * HW + p0 + pp;
      uint4 e, o;
      gatherB(src, e, o);
      *(uint4*)&Bs[kc][pp][0] = e;
      *(uint4*)&Bs[kc][pp + 1][0] = o;
    }
    __syncthreads();
    bf16x8 af[4], bfv[4];
#pragma unroll
    for (int i = 0; i < 4; ++i) {
      af[i] = *(const bf16x8*)&As[qd][rb + i * 16 + ln][0];
      bfv[i] = *(const bf16x8*)&Bs[qd][cb + i * 16 + ln][0];
    }
#pragma unroll
    for (int i = 0; i < 4; ++i)
#pragma unroll
      for (int j = 0; j < 4; ++j)
        acc[i][j] = __builtin_amdgcn_mfma_f32_16x16x32_bf16(af[i], bfv[j],
                                                            acc[i][j], 0, 0, 0);
    __syncthreads();
  }
  size_t ybase = (size_t)b * M * HW;
#pragma unroll
  for (int i = 0; i < 4; ++i) {
    int obase = o0 + rb + i * 16 + qd * 4;
#pragma unroll
    for (int j = 0; j < 4; ++j) {
      int p = p0 + cb + j * 16 + ln;
#pragma unroll
      for (int rr = 0; rr < 4; ++rr) {
        int o = obase + rr;
        size_t idx = ybase + (size_t)o * HW + p;
        float v = acc[i][j][rr];
        float r = AUXF32 ? ((const float*)aux)[idx]
                         : bf2f((u32)((const u16*)aux)[idx]);
        v = r + v * scale[o];
        if (OUTF32) ((float*)Yv)[idx] = v;
        else        ((u16*)Yv)[idx] = f2bf(v);
      }
    }
  }
}

// ------- fused LN2(over 256 ch) + v-multiply + conv1x1 GEMM (wp1 path) ------
// Weights pre-converted bf16 (Wbf = S1, layout [c0c][chl][row][8]).
__global__ __launch_bounds__(256, 2)
void lngemm_k(const u16* __restrict__ Wbf, const u16* __restrict__ X,
              u16* __restrict__ Y, const float* __restrict__ aux,
              const float* __restrict__ scale, const float* __restrict__ gw,
              const float* __restrict__ gb)
{
  __shared__ __align__(16) u16 At[32][128][8];   // full-K attn tile, 64 KB
  __shared__ __align__(16) u16 As[4][128][8];    // weight chunk, 8 KB
  __shared__ float stm[128], str[128];           // per-pixel mean / rstd
  int n0g = blockIdx.x << 7;
  int b = n0g >> 16;
  int p0 = n0g & (HW - 1);
  const u16* Xb = X + (size_t)b * 768 * HW;
  int t = threadIdx.x;
  int lane = t & 63, wv = t >> 6;
  int rb = (wv & 1) << 6, cb = (wv >> 1) << 6;
  int qd = lane >> 4, ln = lane & 15;
  // ---- stage full attn tile (q-slot, channels 0..255)
#pragma unroll
  for (int it = 0; it < 8; ++it) {
    int kc = (t >> 6) + it * 4;
    int pp = (t & 63) << 1;
    const u16* src = Xb + (size_t)(kc * 8) * HW + p0 + pp;
    uint4 e, o;
    gatherB(src, e, o);
    *(uint4*)&At[kc][pp][0] = e;
    *(uint4*)&At[kc][pp + 1][0] = o;
  }
  __syncthreads();
  // ---- per-pixel LN stats (order matches ln2v exactly)
  if (t < 128) {
    float s0 = 0.f, q0 = 0.f;
    for (int cg = 0; cg < 128; ++cg) {
      u32 u = *(const u32*)&At[cg >> 2][t][(cg & 3) << 1];
      float a = bf2f(u & 0xffffu);
      s0 += a; q0 += a * a;
      float d = bf2f(u >> 16);
      s0 += d; q0 += d * d;
    }
    const float inv = 1.0f / 256.0f;
    float m0 = s0 * inv;
    stm[t] = m0;
    str[t] = rsqrtf(fmaxf(q0 * inv - m0 * m0, 0.f) + 1e-6f);
  }
  __syncthreads();
  f32x4 acc[4][4] = {};
  for (int c0 = 0; c0 < 256; c0 += 32) {
    // stage pre-swizzled bf16 weight chunk: 512 uint4 linear copy
    {
      const uint4* wsrc = (const uint4*)(Wbf + (size_t)(c0 >> 5) * 4096);
      ((uint4*)As)[t] = wsrc[t];
      ((uint4*)As)[t + 256] = wsrc[t + 256];
    }
    // normalize this chunk in place, fused with v multiply
    {
      int kcg = (c0 >> 3) + (t >> 6);
      int pp = (t & 63) << 1;
      const u16* vsrc = Xb + (size_t)(512 + kcg * 8) * HW + p0 + pp;
      uint4 ve, vo;
      gatherB(vsrc, ve, vo);
      float w8[8], b8[8];
#pragma unroll
      for (int j = 0; j < 8; ++j) {
        w8[j] = gw[kcg * 8 + j];
        b8[j] = gb[kcg * 8 + j];
      }
      float m0 = stm[pp], r0 = str[pp];
      float m1 = stm[pp + 1], r1 = str[pp + 1];
      uint4 e = *(const uint4*)&At[kcg][pp][0];
      uint4 o = *(const uint4*)&At[kcg][pp + 1][0];
      const u32* ew = (const u32*)&e;
      const u32* ow = (const u32*)&o;
      const u32* vew = (const u32*)&ve;
      const u32* vow = (const u32*)&vo;
      u32 re[4], ro[4];
#pragma unroll
      for (int j = 0; j < 4; ++j) {
        float a0 = ((bf2f(ew[j] & 0xffffu) - m0) * r0 * w8[2 * j] + b8[2 * j]) *
                   bf2f(vew[j] & 0xffffu);
        float a1 = ((bf2f(ew[j] >> 16) - m0) * r0 * w8[2 * j + 1] + b8[2 * j + 1]) *
                   bf2f(vew[j] >> 16);
        re[j] = (u32)f2bf(a0) | ((u32)f2bf(a1) << 16);
        float d0 = ((bf2f(ow[j] & 0xffffu) - m1) * r1 * w8[2 * j] + b8[2 * j]) *
                   bf2f(vow[j] & 0xffffu);
        float d1 = ((bf2f(ow[j] >> 16) - m1) * r1 * w8[2 * j + 1] + b8[2 * j + 1]) *
                   bf2f(vow[j] >> 16);
        ro[j] = (u32)f2bf(d0) | ((u32)f2bf(d1) << 16);
      }
      *(uint4*)&At[kcg][pp][0] = *(const uint4*)re;
      *(uint4*)&At[kcg][pp + 1][0] = *(const uint4*)ro;
    }
    __syncthreads();
    bf16x8 af[4], bfv[4];
    int kb = c0 >> 3;
#pragma unroll
    for (int i = 0; i < 4; ++i) {
      af[i] = *(const bf16x8*)&As[qd][rb + i * 16 + ln][0];
      bfv[i] = *(const bf16x8*)&At[kb + qd][cb + i * 16 + ln][0];
    }
#pragma unroll
    for (int i = 0; i < 4; ++i)
#pragma unroll
      for (int j = 0; j < 4; ++j)
        acc[i][j] = __builtin_amdgcn_mfma_f32_16x16x32_bf16(af[i], bfv[j],
                                                            acc[i][j], 0, 0, 0);
    __syncthreads();
  }
  size_t ybase = (size_t)b * 128 * HW;
#pragma unroll
  for (int i = 0; i < 4; ++i) {
    int obase = rb + i * 16 + qd * 4;
#pragma unroll
    for (int j = 0; j < 4; ++j) {
      int p = p0 + cb + j * 16 + ln;
#pragma unroll
      for (int rr = 0; rr < 4; ++rr) {
        int o = obase + rr;
        size_t idx = ybase + (size_t)o * HW + p;
        float v = acc[i][j][rr];
        float r = aux[idx];
        Y[idx] = f2bf(r + v * scale[o]);
      }
    }
  }
}

// ------- folded conv1x1 GEMM, K=128, pre-converted bf16 weights -------------
// Wbf layout [mt][kc16][row128][8]; stage = linear 2048-uint4 copy per tile.
template <int EPI>
__global__ __launch_bounds__(256, 2)
void gemmf_k(const u16* __restrict__ Wbf, const u16* __restrict__ X,
             u16* __restrict__ Y, const float* __restrict__ bias,
             int MT, int xbatch)
{
  __shared__ __align__(16) u16 Bs[16][128][8];   // full-K B tile, 32 KB
  __shared__ __align__(16) u16 As[16][128][8];   // full-K A tile, 32 KB
  int n0g = blockIdx.x << 7;
  int b = n0g >> 16;
  int p0 = n0g & (HW - 1);
  const u16* Xb = X + (size_t)b * xbatch * HW;
  int t = threadIdx.x;
  int lane = t & 63, wv = t >> 6;
  int rb = (wv & 1) << 6, cb = (wv >> 1) << 6;
  int qd = lane >> 4, ln = lane & 15;
#pragma unroll
  for (int it = 0; it < 4; ++it) {
    int tt = t + it * 256;
    int pp = (tt & 63) << 1;
    int kc = tt >> 6;
    const u16* src = Xb + (size_t)(kc * 8) * HW + p0 + pp;
    uint4 e, o;
    gatherB(src, e, o);
    *(uint4*)&Bs[kc][pp][0] = e;
    *(uint4*)&Bs[kc][pp + 1][0] = o;
  }
  int M = MT << 7;
  size_t ybase = (size_t)b * M * HW;
  for (int mt = 0; mt < MT; ++mt) {
    __syncthreads();   // prior tile's MFMA reads done (mt=0: B writes done)
    {
      const uint4* wsrc = (const uint4*)(Wbf + (size_t)mt * 16384);
#pragma unroll
      for (int it = 0; it < 8; ++it)
        ((uint4*)As)[t + it * 256] = wsrc[t + it * 256];
    }
    __syncthreads();
    f32x4 acc[4][4] = {};
#pragma unroll
    for (int s = 0; s < 4; ++s) {
      bf16x8 af[4], bfv[4];
#pragma unroll
      for (int i = 0; i < 4; ++i) {
        af[i] = *(const bf16x8*)&As[s * 4 + qd][rb + i * 16 + ln][0];
        bfv[i] = *(const bf16x8*)&Bs[s * 4 + qd][cb + i * 16 + ln][0];
      }
#pragma unroll
      for (int i = 0; i < 4; ++i)
#pragma unroll
        for (int j = 0; j < 4; ++j)
          acc[i][j] = __builtin_amdgcn_mfma_f32_16x16x32_bf16(af[i], bfv[j],
                                                              acc[i][j], 0, 0, 0);
    }
    int o0 = mt << 7;
#pragma unroll
    for (int i = 0; i < 4; ++i) {
      int obase = o0 + rb + i * 16 + qd * 4;
#pragma unroll
      for (int j = 0; j < 4; ++j) {
        int p = p0 + cb + j * 16 + ln;
#pragma unroll
        for (int rr = 0; rr < 4; ++rr) {
          int o = obase + rr;
          float v = acc[i][j][rr];
          if (EPI == 1) v += bias[o];
          Y[ybase + (size_t)o * HW + p] = f2bf(v);
        }
      }
    }
  }
}

// ---------------- depthwise 3x3, SAME zero pad, IN-PLACE (bf16 data) --------
// v1 (kept): full 128 KB channel staged per block; 1536 blocks. v2 (half-LDS,
// 2 blk/CU) and v3 (persistent reg-pipelined) both regressed: v3 blew up HBM
// traffic (WRITE 197->377 MB: L2 thrash). v1 has exactly-logical traffic.
__device__ __forceinline__ void ldsrow(const u16* __restrict__ img, int h,
                                       int w0, float* r) {
  if ((unsigned)h > 255u) {
#pragma unroll
    for (int i = 0; i < 10; ++i) r[i] = 0.f;
    return;
  }
  const u16* rp = img + (h << 8) + w0;
  float c[8];
  unpack8(*(const uint4*)rp, c);
#pragma unroll
  for (int i = 0; i < 8; ++i) r[i + 1] = c[i];
  r[0] = (w0 > 0) ? bf2f((u32)rp[-1]) : 0.f;
  r[9] = (w0 < 248) ? bf2f((u32)rp[8]) : 0.f;
}

__global__ __launch_bounds__(1024)
void dwip_k(u16* __restrict__ buf, const float* __restrict__ wt, int C)
{
  __shared__ __align__(16) u16 img[65536];   // 128 KB: full channel
  int bc = blockIdx.x;                       // b*C + c
  int c = bc % C;
  size_t base = (size_t)bc << 16;
  int t = threadIdx.x;
  uint4* simg = (uint4*)img;
  const uint4* gsrc = (const uint4*)(buf + base);
#pragma unroll
  for (int it = 0; it < 8; ++it)
    simg[it * 1024 + t] = gsrc[it * 1024 + t];
  float wg[9];
#pragma unroll
  for (int i = 0; i < 9; ++i) wg[i] = wt[c * 9 + i];
  __syncthreads();
  uint4* gdst = (uint4*)(buf + base);
#pragma unroll
  for (int it = 0; it < 8; ++it) {
    int f = it * 1024 + t;
    int h = f >> 5;
    int w0 = (f & 31) << 3;
    float r0[10], r1[10], r2[10];
    ldsrow(img, h - 1, w0, r0);
    ldsrow(img, h,     w0, r1);
    ldsrow(img, h + 1, w0, r2);
    float o[8];
#pragma unroll
    for (int j = 0; j < 8; ++j) {
      float s = 0.f;
#pragma unroll
      for (int dx = 0; dx < 3; ++dx)
        s += r0[j + dx] * wg[dx] + r1[j + dx] * wg[3 + dx] +
             r2[j + dx] * wg[6 + dx];
      o[j] = s;
    }
    uint4 pk;
    pk.x = (u32)f2bf(o[0]) | ((u32)f2bf(o[1]) << 16);
    pk.y = (u32)f2bf(o[2]) | ((u32)f2bf(o[3]) << 16);
    pk.z = (u32)f2bf(o[4]) | ((u32)f2bf(o[5]) << 16);
    pk.w = (u32)f2bf(o[6]) | ((u32)f2bf(o[7]) << 16);
    gdst[f] = pk;   // global write; LDS still holds pristine input
  }
}

// ---------------- fused depthwise-3x3 + gate product (FFN tail) -------------
__device__ __forceinline__ void ldsrow2(const u16* __restrict__ img, int lr,
                                        int w0, float* r) {
  const u16* rp = img + (lr << 8) + w0;
  float c[8];
  unpack8(*(const uint4*)rp, c);
#pragma unroll
  for (int i = 0; i < 8; ++i) r[i + 1] = c[i];
  r[0] = (w0 > 0) ? bf2f((u32)rp[-1]) : 0.f;
  r[9] = (w0 < 248) ? bf2f((u32)rp[8]) : 0.f;
}

__global__ __launch_bounds__(1024)
void dwfuse_k(const u16* __restrict__ h4, const float* __restrict__ wt,
              u16* __restrict__ pr)
{
  __shared__ __align__(16) u16 img[33280];   // 130 rows x 256, 66.5 KB
  int bx = blockIdx.x;
  int b = bx >> 8;
  int c = (bx >> 1) & 127;
  int half = bx & 1;
  int h0 = half << 7;
  int t = threadIdx.x;
  float o1[32];
  size_t obase = ((size_t)((b << 7) + c) << 16);
#pragma unroll
  for (int pass = 0; pass < 2; ++pass) {
    int ch = c + pass * 128;
    size_t gbase = (size_t)((b << 8) + ch) << 16;
    __syncthreads();             // prior pass conv reads complete
    for (int idx = t; idx < 4160; idx += 1024) {
      int lr = idx >> 5, col = idx & 31;
      int gh = h0 - 1 + lr;
      uint4 v = {0, 0, 0, 0};
      if ((unsigned)gh < 256u)
        v = *(const uint4*)(h4 + gbase + ((size_t)gh << 8) + col * 8);
      *(uint4*)&img[(lr << 8) + col * 8] = v;
    }
    float wg[9];
#pragma unroll
    for (int i = 0; i < 9; ++i) wg[i] = wt[ch * 9 + i];
    __syncthreads();
#pragma unroll
    for (int it = 0; it < 4; ++it) {
      int f = it * 1024 + t;
      int lrr = f >> 5;            // 0..127 output row within half
      int w0 = (f & 31) << 3;
      float r0[10], r1[10], r2[10];
      ldsrow2(img, lrr,     w0, r0);  // global row h0+lrr-1
      ldsrow2(img, lrr + 1, w0, r1);
      ldsrow2(img, lrr + 2, w0, r2);
      float o[8];
#pragma unroll
      for (int j = 0; j < 8; ++j) {
        float s = 0.f;
#pragma unroll
        for (int dx = 0; dx < 3; ++dx)
          s += r0[j + dx] * wg[dx] + r1[j + dx] * wg[3 + dx] +
               r2[j + dx] * wg[6 + dx];
        o[j] = s;
      }
      if (pass == 0) {
#pragma unroll
        for (int j = 0; j < 8; ++j) o1[it * 8 + j] = o[j];
      } else {
        uint4 pk;
        pk.x = (u32)f2bf(o1[it*8+0] * o[0]) | ((u32)f2bf(o1[it*8+1] * o[1]) << 16);
        pk.y = (u32)f2bf(o1[it*8+2] * o[2]) | ((u32)f2bf(o1[it*8+3] * o[3]) << 16);
        pk.z = (u32)f2bf(o1[it*8+4] * o[4]) | ((u32)f2bf(o1[it*8+5] * o[5]) << 16);
        pk.w = (u32)f2bf(o1[it*8+6] * o[6]) | ((u32)f2bf(o1[it*8+7] * o[7]) << 16);
        *(uint4*)(pr + obase + ((size_t)(h0 + lrr) << 8) + w0) = pk;
      }
    }
  }
}

// ---------------- patch-FFT attention = 8x8 circular conv per patch/channel -
__global__ __launch_bounds__(256)
void attn_k(u16* __restrict__ qkv)
{
  int wv = threadIdx.x >> 6, lane = threadIdx.x & 63;
  int task = blockIdx.x * 4 + wv;       // 8192 tasks: b(2) x c(256) x strip(16)
  int b = task >> 12;
  int c = (task >> 4) & 255;
  int strip = task & 15;
  int pr = lane >> 5, pw = lane & 31;
  int row = (strip << 4) + (pr << 3);   // patch top row
  size_t qbase = ((size_t)(b * 768 + c) << 16) + ((size_t)row << 8) + pw * 8;
  size_t kbase = qbase + ((size_t)256 << 16);
  u32 qp[8][4];
  u32 ku[8][4];
#pragma unroll
  for (int i = 0; i < 8; ++i) {
    uint4 qv = *(const uint4*)(qkv + qbase + (i << 8));
    uint4 kv = *(const uint4*)(qkv + kbase + (i << 8));
    qp[i][0] = qv.x; qp[i][1] = qv.y; qp[i][2] = qv.z; qp[i][3] = qv.w;
    ku[i][0] = kv.x; ku[i][1] = kv.y; ku[i][2] = kv.z; ku[i][3] = kv.w;
  }
  // pk[r][n] = pack(lo=k[r][n], hi=k[r][(n-1)&7])
  u32 pk[8][8];
#pragma unroll
  for (int r = 0; r < 8; ++r)
#pragma unroll
    for (int n = 0; n < 8; ++n) {
      if (n & 1) {
        u32 x = ku[r][n >> 1];
        pk[r][n] = (x >> 16) | (x << 16);
      } else {
        pk[r][n] = (ku[r][n >> 1] & 0xffffu) |
                   (ku[r][((n + 7) & 7) >> 1] & 0xffff0000u);
      }
    }
#pragma unroll
  for (int m = 0; m < 8; ++m) {
    float a[8] = {};
#pragma unroll
    for (int i = 0; i < 8; ++i) {
      const int r = (m - i) & 7;
#pragma unroll
      for (int t = 0; t < 4; ++t) {
        const u32 q = qp[i][t];
#pragma unroll
        for (int n = 0; n < 8; ++n)
          a[n] = dot2bf(q, pk[r][(n - 2 * t) & 7], a[n]);
      }
    }
    uint4 pko;
    pko.x = (u32)f2bf(a[0]) | ((u32)f2bf(a[1]) << 16);
    pko.y = (u32)f2bf(a[2]) | ((u32)f2bf(a[3]) << 16);
    pko.z = (u32)f2bf(a[4]) | ((u32)f2bf(a[5]) << 16);
    pko.w = (u32)f2bf(a[6]) | ((u32)f2bf(a[7]) << 16);
    *(uint4*)(qkv + qbase + (m << 8)) = pko;
  }
}

extern "C" void kernel_launch(void* const* d_in, const int* in_sizes, int n_in,
                              void* d_out, int out_size, void* d_ws, size_t ws_size,
                              hipStream_t stream)
{
  (void)in_sizes; (void)n_in; (void)out_size; (void)ws_size;
  const float* x    = (const float*)d_in[0];
  const float* n1w  = (const float*)d_in[1];
  const float* n1b  = (const float*)d_in[2];
  const float* wh1  = (const float*)d_in[3];
  const float* wdw1 = (const float*)d_in[4];
  const float* n2w  = (const float*)d_in[5];
  const float* n2b  = (const float*)d_in[6];
  const float* wp1  = (const float*)d_in[7];
  const float* n3w  = (const float*)d_in[8];
  const float* n3b  = (const float*)d_in[9];
  const float* wh2  = (const float*)d_in[10];
  const float* bh2  = (const float*)d_in[11];
  const float* wdw2 = (const float*)d_in[12];
  const float* wp2  = (const float*)d_in[13];
  const float* sc1  = (const float*)d_in[14];
  const float* sc2  = (const float*)d_in[15];
  float* out = (float*)d_out;
  u16* ws = (u16*)d_ws;

  // workspace (u16 elems), peak ~235 MB:
  //   A = ws          : (2,768,HW)  hidden -> qkv -> attn (raw, in q-slot)
  //                     later: h3 [0,16.7M) | h4 [16.7M,50.3M) | pr [0,16.7M)
  //   B = ws + 100.7M : (2,128,HW)  hln -> xmid (bf16)
  // d_out doubles as bf16-weight scratch (dead until final kernel overwrites):
  //   S0=wh1bf [0,98304) | S1=wp1bf [98304,131072) | S2=wh2bf [131072,163840)
  u16* A = ws;
  u16* B = ws + 100663296;
  u16* h3 = A;
  u16* h4 = A + 16777216;
  u16* pr = A;
  u16* S = (u16*)d_out;

  wprep_k<<<640, 256, 0, stream>>>(wh1, wp1, wh2, S);                        // bf16 weights
  ln_k<1><<<256, 256, 0, stream>>>(x, n1w, n1b, B, 128);                     // hln
  gemmf_k<0><<<1024, 256, 0, stream>>>(S, B, A, nullptr, 6, 128);            // hidden
  dwip_k<<<1536, 1024, 0, stream>>>(A, wdw1, 768);                           // qkv
  attn_k<<<2048, 256, 0, stream>>>(A);                                       // attn -> q-slot
  lngemm_k<<<1024, 256, 0, stream>>>(S + 98304, A, B, x, sc1, n2w, n2b);     // LN2+v*+wp1 -> B
  ln_k<0><<<256, 256, 0, stream>>>(B, n3w, n3b, h3, 128);
  gemmf_k<1><<<1024, 256, 0, stream>>>(S + 131072, h3, h4, bh2, 2, 128);     // h4
  dwfuse_k<<<512, 1024, 0, stream>>>(h4, wdw2, pr);                          // pr = g1*g2
  gemm_k<0,1><<<1024, 256, 0, stream>>>(wp2, pr, out, B, sc2, 128, 128, 128);
}

// Round 7
// 489.434 us; speedup vs baseline: 1.5656x; 1.2716x over previous
//
#include <hip/hip_runtime.h>

typedef unsigned short u16;
typedef unsigned int u32;
typedef __attribute__((ext_vector_type(8))) short bf16x8;
typedef __attribute__((ext_vector_type(4))) float f32x4;

#define HW 65536

__device__ __forceinline__ float bf2f(u32 v) { return __uint_as_float(v << 16); }
__device__ __forceinline__ u16 f2bf(float f) {
  u32 u = __float_as_uint(f);
  u += 0x7fffu + ((u >> 16) & 1u);   // RNE; inputs are finite
  return (u16)(u >> 16);
}

// packed bf16 dot2: d = a.l*b.l + a.h*b.h + d  (CDNA VOP3P v_dot2_f32_bf16)
__device__ __forceinline__ float dot2bf(u32 a, u32 b, float d) {
  asm("v_dot2_f32_bf16 %0, %1, %2, %0" : "+v"(d) : "v"(a), "v"(b));
  return d;
}

__device__ __forceinline__ void unpack8(uint4 u, float r[8]) {
  r[0] = bf2f(u.x & 0xffffu); r[1] = bf2f(u.x >> 16);
  r[2] = bf2f(u.y & 0xffffu); r[3] = bf2f(u.y >> 16);
  r[4] = bf2f(u.z & 0xffffu); r[5] = bf2f(u.z >> 16);
  r[6] = bf2f(u.w & 0xffffu); r[7] = bf2f(u.w >> 16);
}

// ---- weight prep: convert wh1/wp1/wh2 to bf16, pre-swizzled into the exact
// LDS As layouts, into d_out scratch (dead until final kernel overwrites all).
//   S0 = S         [98304): wh1 [mt6][kc16][row128][j8]
//   S1 = S + 98304 [32768): wp1 [c0c8][chl4][row128][j8]
//   S2 = S +131072 [32768): wh2 [mt2][kc16][row128][j8]
__global__ __launch_bounds__(256)
void wprep_k(const float* __restrict__ wh1, const float* __restrict__ wp1,
             const float* __restrict__ wh2, u16* __restrict__ S)
{
  int i = blockIdx.x * 256 + threadIdx.x;   // 0..163839
  if (i < 98304) {
    int j = i & 7, row = (i >> 3) & 127, kc = (i >> 10) & 15, mt = i >> 14;
    S[i] = f2bf(wh1[(mt * 128 + row) * 128 + kc * 8 + j]);
  } else if (i < 131072) {
    int k = i - 98304;
    int j = k & 7, row = (k >> 3) & 127, chl = (k >> 10) & 3, c0c = k >> 12;
    S[i] = f2bf(wp1[row * 256 + c0c * 32 + chl * 8 + j]);
  } else if (i < 163840) {
    int k = i - 131072;
    int j = k & 7, row = (k >> 3) & 127, kc = (k >> 10) & 15, mt = k >> 14;
    S[i] = f2bf(wh2[(mt * 128 + row) * 128 + kc * 8 + j]);
  }
}

// ---------------- LN1 (f32 input, 128 ch), single-pass via LDS tile --------
// Replaces 2-pass ln_k<1>: stage 128px x 128ch f32 (64 KB) once, per-pixel
// stats from LDS in EXACT ln order (serial ascending c, f32 adds), normalize
// from LDS -> bf16 out. Saves the 134 MB second read of x.
__global__ __launch_bounds__(256, 2)
void ln1_k(const float* __restrict__ x, const float* __restrict__ gw,
           const float* __restrict__ gb, u16* __restrict__ y)
{
  __shared__ float xt[128][128];            // [ch][px] 64 KB
  __shared__ float stm[128], str[128];
  int n0g = blockIdx.x << 7;                // 1024 blocks x 128 px
  int b = n0g >> 16;
  int p0 = n0g & (HW - 1);
  const float* xb = x + (size_t)b * 128 * HW + p0;
  u16* yb = y + (size_t)b * 128 * HW + p0;
  int t = threadIdx.x;
#pragma unroll
  for (int it = 0; it < 16; ++it) {
    int idx = t + it * 256;                 // 0..4095 float4 slots
    int ch = idx >> 5;
    int p4 = (idx & 31) << 2;
    *(float4*)&xt[ch][p4] = *(const float4*)(xb + (size_t)ch * HW + p4);
  }
  __syncthreads();
  if (t < 128) {
    float s = 0.f, q = 0.f;
    for (int c = 0; c < 128; ++c) {
      float a = xt[c][t];
      s += a; q += a * a;
    }
    const float inv = 1.0f / 128.0f;
    float m = s * inv;
    stm[t] = m;
    str[t] = rsqrtf(fmaxf(q * inv - m * m, 0.f) + 1e-6f);
  }
  __syncthreads();
  int p2 = (t & 63) << 1;
  int c0 = t >> 6;
  float m0 = stm[p2], r0 = str[p2], m1 = stm[p2 + 1], r1 = str[p2 + 1];
#pragma unroll
  for (int k = 0; k < 32; ++k) {
    int c = c0 + k * 4;
    float w = gw[c], bb = gb[c];
    float a = (xt[c][p2] - m0) * r0 * w + bb;
    float d = (xt[c][p2 + 1] - m1) * r1 * w + bb;
    *(u32*)(yb + (size_t)c * HW + p2) = (u32)f2bf(a) | ((u32)f2bf(d) << 16);
  }
}

// ---- B-tile gather helper: u32 = 2 adjacent pixels, 8 channels -> 2 uint4 --
__device__ __forceinline__ void gatherB(const u16* __restrict__ src,
                                        uint4& e, uint4& o)
{
  u32 w0 = *(const u32*)(src);
  u32 w1 = *(const u32*)(src + HW);
  u32 w2 = *(const u32*)(src + 2 * HW);
  u32 w3 = *(const u32*)(src + 3 * HW);
  u32 w4 = *(const u32*)(src + 4 * HW);
  u32 w5 = *(const u32*)(src + 5 * HW);
  u32 w6 = *(const u32*)(src + 6 * HW);
  u32 w7 = *(const u32*)(src + 7 * HW);
  e.x = (w0 & 0xffffu) | (w1 << 16);
  e.y = (w2 & 0xffffu) | (w3 << 16);
  e.z = (w4 & 0xffffu) | (w5 << 16);
  e.w = (w6 & 0xffffu) | (w7 << 16);
  o.x = (w0 >> 16) | (w1 & 0xffff0000u);
  o.y = (w2 >> 16) | (w3 & 0xffff0000u);
  o.z = (w4 >> 16) | (w5 & 0xffff0000u);
  o.w = (w6 >> 16) | (w7 & 0xffff0000u);
}

// ---------------- chunked conv1x1 GEMM (final wp2 case, f32 weights) --------
// Epilogue: res[o,p] + acc*scale[o]. AUXF32: residual fp32. OUTF32: Y fp32.
template <int AUXF32, int OUTF32>
__global__ __launch_bounds__(256, 2)
void gemm_k(const float* __restrict__ Wt, const u16* __restrict__ X,
            void* __restrict__ Yv, const void* __restrict__ aux,
            const float* __restrict__ scale, int M, int K, int xbatch)
{
  __shared__ __align__(16) u16 As[4][128][8];   // [kchunk][o][8]
  __shared__ __align__(16) u16 Bs[4][128][8];   // [kchunk][pixel][8]
  int mtiles = M >> 7;
  int mt = blockIdx.x % mtiles;
  int ntile = blockIdx.x / mtiles;
  int n0g = ntile << 7;
  int b = n0g >> 16;
  int p0 = n0g & (HW - 1);
  int o0 = mt << 7;
  const u16* Xb = X + (size_t)b * xbatch * HW;
  int t = threadIdx.x;
  int lane = t & 63, wv = t >> 6;
  int rb = (wv & 1) << 6, cb = (wv >> 1) << 6;
  int qd = lane >> 4, ln = lane & 15;
  f32x4 acc[4][4] = {};
  for (int c0 = 0; c0 < K; c0 += 32) {
#pragma unroll
    for (int it = 0; it < 2; ++it) {
      int tt = t + it * 256;
      int row = tt >> 2, ch = tt & 3;
      const float* wsrc = Wt + (size_t)(o0 + row) * K + c0 + ch * 8;
      uint4 pk;
      pk.x = (u32)f2bf(wsrc[0]) | ((u32)f2bf(wsrc[1]) << 16);
      pk.y = (u32)f2bf(wsrc[2]) | ((u32)f2bf(wsrc[3]) << 16);
      pk.z = (u32)f2bf(wsrc[4]) | ((u32)f2bf(wsrc[5]) << 16);
      pk.w = (u32)f2bf(wsrc[6]) | ((u32)f2bf(wsrc[7]) << 16);
      *(uint4*)&As[ch][row][0] = pk;
    }
    {
      int pp = (t & 63) << 1;
      int kc = t >> 6;
      const u16* src = Xb + (size_t)(c0 + kc * 8) * HW + p0 + pp;
      uint4 e, o;
      gatherB(src, e, o);
      *(uint4*)&Bs[kc][pp][0] = e;
      *(uint4*)&Bs[kc][pp + 1][0] = o;
    }
    __syncthreads();
    bf16x8 af[4], bfv[4];
#pragma unroll
    for (int i = 0; i < 4; ++i) {
      af[i] = *(const bf16x8*)&As[qd][rb + i * 16 + ln][0];
      bfv[i] = *(const bf16x8*)&Bs[qd][cb + i * 16 + ln][0];
    }
#pragma unroll
    for (int i = 0; i < 4; ++i)
#pragma unroll
      for (int j = 0; j < 4; ++j)
        acc[i][j] = __builtin_amdgcn_mfma_f32_16x16x32_bf16(af[i], bfv[j],
                                                            acc[i][j], 0, 0, 0);
    __syncthreads();
  }
  size_t ybase = (size_t)b * M * HW;
#pragma unroll
  for (int i = 0; i < 4; ++i) {
    int obase = o0 + rb + i * 16 + qd * 4;
#pragma unroll
    for (int j = 0; j < 4; ++j) {
      int p = p0 + cb + j * 16 + ln;
#pragma unroll
      for (int rr = 0; rr < 4; ++rr) {
        int o = obase + rr;
        size_t idx = ybase + (size_t)o * HW + p;
        float v = acc[i][j][rr];
        float r = AUXF32 ? ((const float*)aux)[idx]
                         : bf2f((u32)((const u16*)aux)[idx]);
        v = r + v * scale[o];
        if (OUTF32) ((float*)Yv)[idx] = v;
        else        ((u16*)Yv)[idx] = f2bf(v);
      }
    }
  }
}

// ------- fused LN2(over 256 ch) + v-multiply + conv1x1 GEMM (wp1 path) ------
// Weights pre-converted bf16 (Wbf = S1, layout [c0c][chl][row][8]).
__global__ __launch_bounds__(256, 2)
void lngemm_k(const u16* __restrict__ Wbf, const u16* __restrict__ X,
              u16* __restrict__ Y, const float* __restrict__ aux,
              const float* __restrict__ scale, const float* __restrict__ gw,
              const float* __restrict__ gb)
{
  __shared__ __align__(16) u16 At[32][128][8];   // full-K attn tile, 64 KB
  __shared__ __align__(16) u16 As[4][128][8];    // weight chunk, 8 KB
  __shared__ float stm[128], str[128];           // per-pixel mean / rstd
  int n0g = blockIdx.x << 7;
  int b = n0g >> 16;
  int p0 = n0g & (HW - 1);
  const u16* Xb = X + (size_t)b * 768 * HW;
  int t = threadIdx.x;
  int lane = t & 63, wv = t >> 6;
  int rb = (wv & 1) << 6, cb = (wv >> 1) << 6;
  int qd = lane >> 4, ln = lane & 15;
  // ---- stage full attn tile (q-slot, channels 0..255)
#pragma unroll
  for (int it = 0; it < 8; ++it) {
    int kc = (t >> 6) + it * 4;
    int pp = (t & 63) << 1;
    const u16* src = Xb + (size_t)(kc * 8) * HW + p0 + pp;
    uint4 e, o;
    gatherB(src, e, o);
    *(uint4*)&At[kc][pp][0] = e;
    *(uint4*)&At[kc][pp + 1][0] = o;
  }
  __syncthreads();
  // ---- per-pixel LN stats (order matches ln2v exactly)
  if (t < 128) {
    float s0 = 0.f, q0 = 0.f;
    for (int cg = 0; cg < 128; ++cg) {
      u32 u = *(const u32*)&At[cg >> 2][t][(cg & 3) << 1];
      float a = bf2f(u & 0xffffu);
      s0 += a; q0 += a * a;
      float d = bf2f(u >> 16);
      s0 += d; q0 += d * d;
    }
    const float inv = 1.0f / 256.0f;
    float m0 = s0 * inv;
    stm[t] = m0;
    str[t] = rsqrtf(fmaxf(q0 * inv - m0 * m0, 0.f) + 1e-6f);
  }
  __syncthreads();
  f32x4 acc[4][4] = {};
  for (int c0 = 0; c0 < 256; c0 += 32) {
    // stage pre-swizzled bf16 weight chunk: 512 uint4 linear copy
    {
      const uint4* wsrc = (const uint4*)(Wbf + (size_t)(c0 >> 5) * 4096);
      ((uint4*)As)[t] = wsrc[t];
      ((uint4*)As)[t + 256] = wsrc[t + 256];
    }
    // normalize this chunk in place, fused with v multiply
    {
      int kcg = (c0 >> 3) + (t >> 6);
      int pp = (t & 63) << 1;
      const u16* vsrc = Xb + (size_t)(512 + kcg * 8) * HW + p0 + pp;
      uint4 ve, vo;
      gatherB(vsrc, ve, vo);
      float w8[8], b8[8];
#pragma unroll
      for (int j = 0; j < 8; ++j) {
        w8[j] = gw[kcg * 8 + j];
        b8[j] = gb[kcg * 8 + j];
      }
      float m0 = stm[pp], r0 = str[pp];
      float m1 = stm[pp + 1], r1 = str[pp + 1];
      uint4 e = *(const uint4*)&At[kcg][pp][0];
      uint4 o = *(const uint4*)&At[kcg][pp + 1][0];
      const u32* ew = (const u32*)&e;
      const u32* ow = (const u32*)&o;
      const u32* vew = (const u32*)&ve;
      const u32* vow = (const u32*)&vo;
      u32 re[4], ro[4];
#pragma unroll
      for (int j = 0; j < 4; ++j) {
        float a0 = ((bf2f(ew[j] & 0xffffu) - m0) * r0 * w8[2 * j] + b8[2 * j]) *
                   bf2f(vew[j] & 0xffffu);
        float a1 = ((bf2f(ew[j] >> 16) - m0) * r0 * w8[2 * j + 1] + b8[2 * j + 1]) *
                   bf2f(vew[j] >> 16);
        re[j] = (u32)f2bf(a0) | ((u32)f2bf(a1) << 16);
        float d0 = ((bf2f(ow[j] & 0xffffu) - m1) * r1 * w8[2 * j] + b8[2 * j]) *
                   bf2f(vow[j] & 0xffffu);
        float d1 = ((bf2f(ow[j] >> 16) - m1) * r1 * w8[2 * j + 1] + b8[2 * j + 1]) *
                   bf2f(vow[j] >> 16);
        ro[j] = (u32)f2bf(d0) | ((u32)f2bf(d1) << 16);
      }
      *(uint4*)&At[kcg][pp][0] = *(const uint4*)re;
      *(uint4*)&At[kcg][pp + 1][0] = *(const uint4*)ro;
    }
    __syncthreads();
    bf16x8 af[4], bfv[4];
    int kb = c0 >> 3;
#pragma unroll
    for (int i = 0; i < 4; ++i) {
      af[i] = *(const bf16x8*)&As[qd][rb + i * 16 + ln][0];
      bfv[i] = *(const bf16x8*)&At[kb + qd][cb + i * 16 + ln][0];
    }
#pragma unroll
    for (int i = 0; i < 4; ++i)
#pragma unroll
      for (int j = 0; j < 4; ++j)
        acc[i][j] = __builtin_amdgcn_mfma_f32_16x16x32_bf16(af[i], bfv[j],
                                                            acc[i][j], 0, 0, 0);
    __syncthreads();
  }
  size_t ybase = (size_t)b * 128 * HW;
#pragma unroll
  for (int i = 0; i < 4; ++i) {
    int obase = rb + i * 16 + qd * 4;
#pragma unroll
    for (int j = 0; j < 4; ++j) {
      int p = p0 + cb + j * 16 + ln;
#pragma unroll
      for (int rr = 0; rr < 4; ++rr) {
        int o = obase + rr;
        size_t idx = ybase + (size_t)o * HW + p;
        float v = acc[i][j][rr];
        float r = aux[idx];
        Y[idx] = f2bf(r + v * scale[o]);
      }
    }
  }
}

// ------- folded conv1x1 GEMM, K=128, pre-converted bf16 weights -------------
// Wbf layout [mt][kc16][row128][8]; stage = linear 2048-uint4 copy per tile.
template <int EPI>
__global__ __launch_bounds__(256, 2)
void gemmf_k(const u16* __restrict__ Wbf, const u16* __restrict__ X,
             u16* __restrict__ Y, const float* __restrict__ bias,
             int MT, int xbatch)
{
  __shared__ __align__(16) u16 Bs[16][128][8];   // full-K B tile, 32 KB
  __shared__ __align__(16) u16 As[16][128][8];   // full-K A tile, 32 KB
  int n0g = blockIdx.x << 7;
  int b = n0g >> 16;
  int p0 = n0g & (HW - 1);
  const u16* Xb = X + (size_t)b * xbatch * HW;
  int t = threadIdx.x;
  int lane = t & 63, wv = t >> 6;
  int rb = (wv & 1) << 6, cb = (wv >> 1) << 6;
  int qd = lane >> 4, ln = lane & 15;
#pragma unroll
  for (int it = 0; it < 4; ++it) {
    int tt = t + it * 256;
    int pp = (tt & 63) << 1;
    int kc = tt >> 6;
    const u16* src = Xb + (size_t)(kc * 8) * HW + p0 + pp;
    uint4 e, o;
    gatherB(src, e, o);
    *(uint4*)&Bs[kc][pp][0] = e;
    *(uint4*)&Bs[kc][pp + 1][0] = o;
  }
  int M = MT << 7;
  size_t ybase = (size_t)b * M * HW;
  for (int mt = 0; mt < MT; ++mt) {
    __syncthreads();   // prior tile's MFMA reads done (mt=0: B writes done)
    {
      const uint4* wsrc = (const uint4*)(Wbf + (size_t)mt * 16384);
#pragma unroll
      for (int it = 0; it < 8; ++it)
        ((uint4*)As)[t + it * 256] = wsrc[t + it * 256];
    }
    __syncthreads();
    f32x4 acc[4][4] = {};
#pragma unroll
    for (int s = 0; s < 4; ++s) {
      bf16x8 af[4], bfv[4];
#pragma unroll
      for (int i = 0; i < 4; ++i) {
        af[i] = *(const bf16x8*)&As[s * 4 + qd][rb + i * 16 + ln][0];
        bfv[i] = *(const bf16x8*)&Bs[s * 4 + qd][cb + i * 16 + ln][0];
      }
#pragma unroll
      for (int i = 0; i < 4; ++i)
#pragma unroll
        for (int j = 0; j < 4; ++j)
          acc[i][j] = __builtin_amdgcn_mfma_f32_16x16x32_bf16(af[i], bfv[j],
                                                              acc[i][j], 0, 0, 0);
    }
    int o0 = mt << 7;
#pragma unroll
    for (int i = 0; i < 4; ++i) {
      int obase = o0 + rb + i * 16 + qd * 4;
#pragma unroll
      for (int j = 0; j < 4; ++j) {
        int p = p0 + cb + j * 16 + ln;
#pragma unroll
        for (int rr = 0; rr < 4; ++rr) {
          int o = obase + rr;
          float v = acc[i][j][rr];
          if (EPI == 1) v += bias[o];
          Y[ybase + (size_t)o * HW + p] = f2bf(v);
        }
      }
    }
  }
}

// ------- fused LN3 + folded conv1x1 GEMM (wh2 path, K=128, bias) ------------
// Replaces ln_k<0> + gemmf_k<1>: stats over the staged Bs tile in EXACT ln
// order (per pixel, ascending c, f32 adds), normalize to bf16 in place in
// LDS (identical values to the old h3 buffer), then the usual MT GEMM loop.
// Eliminates the h3 round trip (134 MB) and one launch.
__global__ __launch_bounds__(256, 2)
void lngemmf_k(const u16* __restrict__ Wbf, const u16* __restrict__ X,
               u16* __restrict__ Y, const float* __restrict__ bias,
               const float* __restrict__ gw, const float* __restrict__ gb,
               int MT, int xbatch)
{
  __shared__ __align__(16) u16 Bs[16][128][8];   // full-K B tile, 32 KB
  __shared__ __align__(16) u16 As[16][128][8];   // full-K A tile, 32 KB
  __shared__ float stm[128], str[128];
  int n0g = blockIdx.x << 7;
  int b = n0g >> 16;
  int p0 = n0g & (HW - 1);
  const u16* Xb = X + (size_t)b * xbatch * HW;
  int t = threadIdx.x;
  int lane = t & 63, wv = t >> 6;
  int rb = (wv & 1) << 6, cb = (wv >> 1) << 6;
  int qd = lane >> 4, ln = lane & 15;
#pragma unroll
  for (int it = 0; it < 4; ++it) {
    int tt = t + it * 256;
    int pp = (tt & 63) << 1;
    int kc = tt >> 6;
    const u16* src = Xb + (size_t)(kc * 8) * HW + p0 + pp;
    uint4 e, o;
    gatherB(src, e, o);
    *(uint4*)&Bs[kc][pp][0] = e;
    *(uint4*)&Bs[kc][pp + 1][0] = o;
  }
  __syncthreads();
  // per-pixel LN stats over 128 ch, ascending-c f32 order (matches ln_k)
  if (t < 128) {
    float s = 0.f, q = 0.f;
    for (int kc = 0; kc < 16; ++kc) {
      float r8[8];
      unpack8(*(const uint4*)&Bs[kc][t][0], r8);
#pragma unroll
      for (int j = 0; j < 8; ++j) {
        float a = r8[j];
        s += a; q += a * a;
      }
    }
    const float inv = 1.0f / 128.0f;
    float m = s * inv;
    stm[t] = m;
    str[t] = rsqrtf(fmaxf(q * inv - m * m, 0.f) + 1e-6f);
  }
  __syncthreads();
  // normalize Bs in place -> bf16 (identical to old h3 values)
  {
    int pp = (t & 63) << 1;
    float m0 = stm[pp], r0 = str[pp];
    float m1 = stm[pp + 1], r1 = str[pp + 1];
#pragma unroll
    for (int mth = 0; mth < 4; ++mth) {
      int kc = (t >> 6) + mth * 4;
      float w8[8], b8[8];
#pragma unroll
      for (int j = 0; j < 8; ++j) {
        w8[j] = gw[kc * 8 + j];
        b8[j] = gb[kc * 8 + j];
      }
      float e8[8], o8[8];
      unpack8(*(const uint4*)&Bs[kc][pp][0], e8);
      unpack8(*(const uint4*)&Bs[kc][pp + 1][0], o8);
      uint4 pe, po;
      u32* pew = (u32*)&pe;
      u32* pow = (u32*)&po;
#pragma unroll
      for (int j = 0; j < 4; ++j) {
        float a0 = (e8[2 * j] - m0) * r0 * w8[2 * j] + b8[2 * j];
        float a1 = (e8[2 * j + 1] - m0) * r0 * w8[2 * j + 1] + b8[2 * j + 1];
        pew[j] = (u32)f2bf(a0) | ((u32)f2bf(a1) << 16);
        float d0 = (o8[2 * j] - m1) * r1 * w8[2 * j] + b8[2 * j];
        float d1 = (o8[2 * j + 1] - m1) * r1 * w8[2 * j + 1] + b8[2 * j + 1];
        pow[j] = (u32)f2bf(d0) | ((u32)f2bf(d1) << 16);
      }
      *(uint4*)&Bs[kc][pp][0] = pe;
      *(uint4*)&Bs[kc][pp + 1][0] = po;
    }
  }
  int M = MT << 7;
  size_t ybase = (size_t)b * M * HW;
  for (int mt = 0; mt < MT; ++mt) {
    __syncthreads();
    {
      const uint4* wsrc = (const uint4*)(Wbf + (size_t)mt * 16384);
#pragma unroll
      for (int it = 0; it < 8; ++it)
        ((uint4*)As)[t + it * 256] = wsrc[t + it * 256];
    }
    __syncthreads();
    f32x4 acc[4][4] = {};
#pragma unroll
    for (int s = 0; s < 4; ++s) {
      bf16x8 af[4], bfv[4];
#pragma unroll
      for (int i = 0; i < 4; ++i) {
        af[i] = *(const bf16x8*)&As[s * 4 + qd][rb + i * 16 + ln][0];
        bfv[i] = *(const bf16x8*)&Bs[s * 4 + qd][cb + i * 16 + ln][0];
      }
#pragma unroll
      for (int i = 0; i < 4; ++i)
#pragma unroll
        for (int j = 0; j < 4; ++j)
          acc[i][j] = __builtin_amdgcn_mfma_f32_16x16x32_bf16(af[i], bfv[j],
                                                              acc[i][j], 0, 0, 0);
    }
    int o0 = mt << 7;
#pragma unroll
    for (int i = 0; i < 4; ++i) {
      int obase = o0 + rb + i * 16 + qd * 4;
#pragma unroll
      for (int j = 0; j < 4; ++j) {
        int p = p0 + cb + j * 16 + ln;
#pragma unroll
        for (int rr = 0; rr < 4; ++rr) {
          int o = obase + rr;
          Y[ybase + (size_t)o * HW + p] = f2bf(acc[i][j][rr] + bias[o]);
        }
      }
    }
  }
}

// ---------------- depthwise 3x3, SAME zero pad, IN-PLACE (bf16 data) --------
// v1 (kept): full 128 KB channel staged per block; 1536 blocks. v2 (half-LDS,
// 2 blk/CU) and v3 (persistent reg-pipelined) both regressed: v3 blew up HBM
// traffic (WRITE 197->377 MB: L2 thrash). v1 has exactly-logical traffic.
__device__ __forceinline__ void ldsrow(const u16* __restrict__ img, int h,
                                       int w0, float* r) {
  if ((unsigned)h > 255u) {
#pragma unroll
    for (int i = 0; i < 10; ++i) r[i] = 0.f;
    return;
  }
  const u16* rp = img + (h << 8) + w0;
  float c[8];
  unpack8(*(const uint4*)rp, c);
#pragma unroll
  for (int i = 0; i < 8; ++i) r[i + 1] = c[i];
  r[0] = (w0 > 0) ? bf2f((u32)rp[-1]) : 0.f;
  r[9] = (w0 < 248) ? bf2f((u32)rp[8]) : 0.f;
}

__global__ __launch_bounds__(1024)
void dwip_k(u16* __restrict__ buf, const float* __restrict__ wt, int C)
{
  __shared__ __align__(16) u16 img[65536];   // 128 KB: full channel
  int bc = blockIdx.x;                       // b*C + c
  int c = bc % C;
  size_t base = (size_t)bc << 16;
  int t = threadIdx.x;
  uint4* simg = (uint4*)img;
  const uint4* gsrc = (const uint4*)(buf + base);
#pragma unroll
  for (int it = 0; it < 8; ++it)
    simg[it * 1024 + t] = gsrc[it * 1024 + t];
  float wg[9];
#pragma unroll
  for (int i = 0; i < 9; ++i) wg[i] = wt[c * 9 + i];
  __syncthreads();
  uint4* gdst = (uint4*)(buf + base);
#pragma unroll
  for (int it = 0; it < 8; ++it) {
    int f = it * 1024 + t;
    int h = f >> 5;
    int w0 = (f & 31) << 3;
    float r0[10], r1[10], r2[10];
    ldsrow(img, h - 1, w0, r0);
    ldsrow(img, h,     w0, r1);
    ldsrow(img, h + 1, w0, r2);
    float o[8];
#pragma unroll
    for (int j = 0; j < 8; ++j) {
      float s = 0.f;
#pragma unroll
      for (int dx = 0; dx < 3; ++dx)
        s += r0[j + dx] * wg[dx] + r1[j + dx] * wg[3 + dx] +
             r2[j + dx] * wg[6 + dx];
      o[j] = s;
    }
    uint4 pk;
    pk.x = (u32)f2bf(o[0]) | ((u32)f2bf(o[1]) << 16);
    pk.y = (u32)f2bf(o[2]) | ((u32)f2bf(o[3]) << 16);
    pk.z = (u32)f2bf(o[4]) | ((u32)f2bf(o[5]) << 16);
    pk.w = (u32)f2bf(o[6]) | ((u32)f2bf(o[7]) << 16);
    gdst[f] = pk;   // global write; LDS still holds pristine input
  }
}

// ---------------- fused depthwise-3x3 + gate product (FFN tail) -------------
__device__ __forceinline__ void ldsrow2(const u16* __restrict__ img, int lr,
                                        int w0, float* r) {
  const u16* rp = img + (lr << 8) + w0;
  float c[8];
  unpack8(*(const uint4*)rp, c);
#pragma unroll
  for (int i = 0; i < 8; ++i) r[i + 1] = c[i];
  r[0] = (w0 > 0) ? bf2f((u32)rp[-1]) : 0.f;
  r[9] = (w0 < 248) ? bf2f((u32)rp[8]) : 0.f;
}

__global__ __launch_bounds__(1024)
void dwfuse_k(const u16* __restrict__ h4, const float* __restrict__ wt,
              u16* __restrict__ pr)
{
  __shared__ __align__(16) u16 img[33280];   // 130 rows x 256, 66.5 KB
  int bx = blockIdx.x;
  int b = bx >> 8;
  int c = (bx >> 1) & 127;
  int half = bx & 1;
  int h0 = half << 7;
  int t = threadIdx.x;
  float o1[32];
  size_t obase = ((size_t)((b << 7) + c) << 16);
#pragma unroll
  for (int pass = 0; pass < 2; ++pass) {
    int ch = c + pass * 128;
    size_t gbase = (size_t)((b << 8) + ch) << 16;
    __syncthreads();             // prior pass conv reads complete
    for (int idx = t; idx < 4160; idx += 1024) {
      int lr = idx >> 5, col = idx & 31;
      int gh = h0 - 1 + lr;
      uint4 v = {0, 0, 0, 0};
      if ((unsigned)gh < 256u)
        v = *(const uint4*)(h4 + gbase + ((size_t)gh << 8) + col * 8);
      *(uint4*)&img[(lr << 8) + col * 8] = v;
    }
    float wg[9];
#pragma unroll
    for (int i = 0; i < 9; ++i) wg[i] = wt[ch * 9 + i];
    __syncthreads();
#pragma unroll
    for (int it = 0; it < 4; ++it) {
      int f = it * 1024 + t;
      int lrr = f >> 5;            // 0..127 output row within half
      int w0 = (f & 31) << 3;
      float r0[10], r1[10], r2[10];
      ldsrow2(img, lrr,     w0, r0);  // global row h0+lrr-1
      ldsrow2(img, lrr + 1, w0, r1);
      ldsrow2(img, lrr + 2, w0, r2);
      float o[8];
#pragma unroll
      for (int j = 0; j < 8; ++j) {
        float s = 0.f;
#pragma unroll
        for (int dx = 0; dx < 3; ++dx)
          s += r0[j + dx] * wg[dx] + r1[j + dx] * wg[3 + dx] +
               r2[j + dx] * wg[6 + dx];
        o[j] = s;
      }
      if (pass == 0) {
#pragma unroll
        for (int j = 0; j < 8; ++j) o1[it * 8 + j] = o[j];
      } else {
        uint4 pk;
        pk.x = (u32)f2bf(o1[it*8+0] * o[0]) | ((u32)f2bf(o1[it*8+1] * o[1]) << 16);
        pk.y = (u32)f2bf(o1[it*8+2] * o[2]) | ((u32)f2bf(o1[it*8+3] * o[3]) << 16);
        pk.z = (u32)f2bf(o1[it*8+4] * o[4]) | ((u32)f2bf(o1[it*8+5] * o[5]) << 16);
        pk.w = (u32)f2bf(o1[it*8+6] * o[6]) | ((u32)f2bf(o1[it*8+7] * o[7]) << 16);
        *(uint4*)(pr + obase + ((size_t)(h0 + lrr) << 8) + w0) = pk;
      }
    }
  }
}

// ---------------- patch-FFT attention = 8x8 circular conv per patch/channel -
__global__ __launch_bounds__(256)
void attn_k(u16* __restrict__ qkv)
{
  int wv = threadIdx.x >> 6, lane = threadIdx.x & 63;
  int task = blockIdx.x * 4 + wv;       // 8192 tasks: b(2) x c(256) x strip(16)
  int b = task >> 12;
  int c = (task >> 4) & 255;
  int strip = task & 15;
  int pr = lane >> 5, pw = lane & 31;
  int row = (strip << 4) + (pr << 3);   // patch top row
  size_t qbase = ((size_t)(b * 768 + c) << 16) + ((size_t)row << 8) + pw * 8;
  size_t kbase = qbase + ((size_t)256 << 16);
  u32 qp[8][4];
  u32 ku[8][4];
#pragma unroll
  for (int i = 0; i < 8; ++i) {
    uint4 qv = *(const uint4*)(qkv + qbase + (i << 8));
    uint4 kv = *(const uint4*)(qkv + kbase + (i << 8));
    qp[i][0] = qv.x; qp[i][1] = qv.y; qp[i][2] = qv.z; qp[i][3] = qv.w;
    ku[i][0] = kv.x; ku[i][1] = kv.y; ku[i][2] = kv.z; ku[i][3] = kv.w;
  }
  // pk[r][n] = pack(lo=k[r][n], hi=k[r][(n-1)&7])
  u32 pk[8][8];
#pragma unroll
  for (int r = 0; r < 8; ++r)
#pragma unroll
    for (int n = 0; n < 8; ++n) {
      if (n & 1) {
        u32 x = ku[r][n >> 1];
        pk[r][n] = (x >> 16) | (x << 16);
      } else {
        pk[r][n] = (ku[r][n >> 1] & 0xffffu) |
                   (ku[r][((n + 7) & 7) >> 1] & 0xffff0000u);
      }
    }
#pragma unroll
  for (int m = 0; m < 8; ++m) {
    float a[8] = {};
#pragma unroll
    for (int i = 0; i < 8; ++i) {
      const int r = (m - i) & 7;
#pragma unroll
      for (int t = 0; t < 4; ++t) {
        const u32 q = qp[i][t];
#pragma unroll
        for (int n = 0; n < 8; ++n)
          a[n] = dot2bf(q, pk[r][(n - 2 * t) & 7], a[n]);
      }
    }
    uint4 pko;
    pko.x = (u32)f2bf(a[0]) | ((u32)f2bf(a[1]) << 16);
    pko.y = (u32)f2bf(a[2]) | ((u32)f2bf(a[3]) << 16);
    pko.z = (u32)f2bf(a[4]) | ((u32)f2bf(a[5]) << 16);
    pko.w = (u32)f2bf(a[6]) | ((u32)f2bf(a[7]) << 16);
    *(uint4*)(qkv + qbase + (m << 8)) = pko;
  }
}

extern "C" void kernel_launch(void* const* d_in, const int* in_sizes, int n_in,
                              void* d_out, int out_size, void* d_ws, size_t ws_size,
                              hipStream_t stream)
{
  (void)in_sizes; (void)n_in; (void)out_size; (void)ws_size;
  const float* x    = (const float*)d_in[0];
  const float* n1w  = (const float*)d_in[1];
  const float* n1b  = (const float*)d_in[2];
  const float* wh1  = (const float*)d_in[3];
  const float* wdw1 = (const float*)d_in[4];
  const float* n2w  = (const float*)d_in[5];
  const float* n2b  = (const float*)d_in[6];
  const float* wp1  = (const float*)d_in[7];
  const float* n3w  = (const float*)d_in[8];
  const float* n3b  = (const float*)d_in[9];
  const float* wh2  = (const float*)d_in[10];
  const float* bh2  = (const float*)d_in[11];
  const float* wdw2 = (const float*)d_in[12];
  const float* wp2  = (const float*)d_in[13];
  const float* sc1  = (const float*)d_in[14];
  const float* sc2  = (const float*)d_in[15];
  float* out = (float*)d_out;
  u16* ws = (u16*)d_ws;

  // workspace (u16 elems), peak ~235 MB:
  //   A = ws          : (2,768,HW)  hidden -> qkv -> attn (raw, in q-slot)
  //                     later: h4 [16.7M,50.3M) | pr [0,16.7M)
  //   B = ws + 100.7M : (2,128,HW)  hln -> xmid (bf16)
  // d_out doubles as bf16-weight scratch (dead until final kernel overwrites):
  //   S0=wh1bf [0,98304) | S1=wp1bf [98304,131072) | S2=wh2bf [131072,163840)
  u16* A = ws;
  u16* B = ws + 100663296;
  u16* h4 = A + 16777216;
  u16* pr = A;
  u16* S = (u16*)d_out;

  wprep_k<<<640, 256, 0, stream>>>(wh1, wp1, wh2, S);                        // bf16 weights
  ln1_k<<<1024, 256, 0, stream>>>(x, n1w, n1b, B);                           // hln (1-pass)
  gemmf_k<0><<<1024, 256, 0, stream>>>(S, B, A, nullptr, 6, 128);            // hidden
  dwip_k<<<1536, 1024, 0, stream>>>(A, wdw1, 768);                           // qkv
  attn_k<<<2048, 256, 0, stream>>>(A);                                       // attn -> q-slot
  lngemm_k<<<1024, 256, 0, stream>>>(S + 98304, A, B, x, sc1, n2w, n2b);     // LN2+v*+wp1 -> B
  lngemmf_k<<<1024, 256, 0, stream>>>(S + 131072, B, h4, bh2, n3w, n3b, 2, 128); // LN3+wh2 -> h4
  dwfuse_k<<<512, 1024, 0, stream>>>(h4, wdw2, pr);                          // pr = g1*g2
  gemm_k<0,1><<<1024, 256, 0, stream>>>(wp2, pr, out, B, sc2, 128, 128, 128);
}

// Round 8
// 454.212 us; speedup vs baseline: 1.6870x; 1.0775x over previous
//
#include <hip/hip_runtime.h>

typedef unsigned short u16;
typedef unsigned int u32;
typedef __attribute__((ext_vector_type(8))) short bf16x8;
typedef __attribute__((ext_vector_type(4))) float f32x4;

#define HW 65536

__device__ __forceinline__ float bf2f(u32 v) { return __uint_as_float(v << 16); }
__device__ __forceinline__ u16 f2bf(float f) {
  u32 u = __float_as_uint(f);
  u += 0x7fffu + ((u >> 16) & 1u);   // RNE; inputs are finite
  return (u16)(u >> 16);
}

// packed bf16 dot2: d = a.l*b.l + a.h*b.h + d  (CDNA VOP3P v_dot2_f32_bf16)
__device__ __forceinline__ float dot2bf(u32 a, u32 b, float d) {
  asm("v_dot2_f32_bf16 %0, %1, %2, %0" : "+v"(d) : "v"(a), "v"(b));
  return d;
}

__device__ __forceinline__ void unpack8(uint4 u, float r[8]) {
  r[0] = bf2f(u.x & 0xffffu); r[1] = bf2f(u.x >> 16);
  r[2] = bf2f(u.y & 0xffffu); r[3] = bf2f(u.y >> 16);
  r[4] = bf2f(u.z & 0xffffu); r[5] = bf2f(u.z >> 16);
  r[6] = bf2f(u.w & 0xffffu); r[7] = bf2f(u.w >> 16);
}

// ---- weight prep: convert wh1/wp1/wh2 to bf16, pre-swizzled into the exact
// LDS As layouts, into d_out scratch (dead until final kernel overwrites all).
//   S0 = S         [98304): wh1 [mt6][kc16][row128][j8]
//   S1 = S + 98304 [32768): wp1 [c0c8][chl4][row128][j8]
//   S2 = S +131072 [32768): wh2 [mt2][kc16][row128][j8]
__global__ __launch_bounds__(256)
void wprep_k(const float* __restrict__ wh1, const float* __restrict__ wp1,
             const float* __restrict__ wh2, u16* __restrict__ S)
{
  int i = blockIdx.x * 256 + threadIdx.x;   // 0..163839
  if (i < 98304) {
    int j = i & 7, row = (i >> 3) & 127, kc = (i >> 10) & 15, mt = i >> 14;
    S[i] = f2bf(wh1[(mt * 128 + row) * 128 + kc * 8 + j]);
  } else if (i < 131072) {
    int k = i - 98304;
    int j = k & 7, row = (k >> 3) & 127, chl = (k >> 10) & 3, c0c = k >> 12;
    S[i] = f2bf(wp1[row * 256 + c0c * 32 + chl * 8 + j]);
  } else if (i < 163840) {
    int k = i - 131072;
    int j = k & 7, row = (k >> 3) & 127, kc = (k >> 10) & 15, mt = k >> 14;
    S[i] = f2bf(wh2[(mt * 128 + row) * 128 + kc * 8 + j]);
  }
}

// ---------------- LN1 (f32 input, 128 ch), single-pass via LDS tile --------
__global__ __launch_bounds__(256, 2)
void ln1_k(const float* __restrict__ x, const float* __restrict__ gw,
           const float* __restrict__ gb, u16* __restrict__ y)
{
  __shared__ float xt[128][128];            // [ch][px] 64 KB
  __shared__ float stm[128], str[128];
  int n0g = blockIdx.x << 7;                // 1024 blocks x 128 px
  int b = n0g >> 16;
  int p0 = n0g & (HW - 1);
  const float* xb = x + (size_t)b * 128 * HW + p0;
  u16* yb = y + (size_t)b * 128 * HW + p0;
  int t = threadIdx.x;
#pragma unroll
  for (int it = 0; it < 16; ++it) {
    int idx = t + it * 256;                 // 0..4095 float4 slots
    int ch = idx >> 5;
    int p4 = (idx & 31) << 2;
    *(float4*)&xt[ch][p4] = *(const float4*)(xb + (size_t)ch * HW + p4);
  }
  __syncthreads();
  if (t < 128) {
    float s = 0.f, q = 0.f;
    for (int c = 0; c < 128; ++c) {
      float a = xt[c][t];
      s += a; q += a * a;
    }
    const float inv = 1.0f / 128.0f;
    float m = s * inv;
    stm[t] = m;
    str[t] = rsqrtf(fmaxf(q * inv - m * m, 0.f) + 1e-6f);
  }
  __syncthreads();
  int p2 = (t & 63) << 1;
  int c0 = t >> 6;
  float m0 = stm[p2], r0 = str[p2], m1 = stm[p2 + 1], r1 = str[p2 + 1];
#pragma unroll
  for (int k = 0; k < 32; ++k) {
    int c = c0 + k * 4;
    float w = gw[c], bb = gb[c];
    float a = (xt[c][p2] - m0) * r0 * w + bb;
    float d = (xt[c][p2 + 1] - m1) * r1 * w + bb;
    *(u32*)(yb + (size_t)c * HW + p2) = (u32)f2bf(a) | ((u32)f2bf(d) << 16);
  }
}

// ---- B-tile gather helper: u32 = 2 adjacent pixels, 8 channels -> 2 uint4 --
__device__ __forceinline__ void gatherB(const u16* __restrict__ src,
                                        uint4& e, uint4& o)
{
  u32 w0 = *(const u32*)(src);
  u32 w1 = *(const u32*)(src + HW);
  u32 w2 = *(const u32*)(src + 2 * HW);
  u32 w3 = *(const u32*)(src + 3 * HW);
  u32 w4 = *(const u32*)(src + 4 * HW);
  u32 w5 = *(const u32*)(src + 5 * HW);
  u32 w6 = *(const u32*)(src + 6 * HW);
  u32 w7 = *(const u32*)(src + 7 * HW);
  e.x = (w0 & 0xffffu) | (w1 << 16);
  e.y = (w2 & 0xffffu) | (w3 << 16);
  e.z = (w4 & 0xffffu) | (w5 << 16);
  e.w = (w6 & 0xffffu) | (w7 << 16);
  o.x = (w0 >> 16) | (w1 & 0xffff0000u);
  o.y = (w2 >> 16) | (w3 & 0xffff0000u);
  o.z = (w4 >> 16) | (w5 & 0xffff0000u);
  o.w = (w6 >> 16) | (w7 & 0xffff0000u);
}

// ---------------- chunked conv1x1 GEMM (final wp2 case, f32 weights) --------
template <int AUXF32, int OUTF32>
__global__ __launch_bounds__(256, 2)
void gemm_k(const float* __restrict__ Wt, const u16* __restrict__ X,
            void* __restrict__ Yv, const void* __restrict__ aux,
            const float* __restrict__ scale, int M, int K, int xbatch)
{
  __shared__ __align__(16) u16 As[4][128][8];   // [kchunk][o][8]
  __shared__ __align__(16) u16 Bs[4][128][8];   // [kchunk][pixel][8]
  int mtiles = M >> 7;
  int mt = blockIdx.x % mtiles;
  int ntile = blockIdx.x / mtiles;
  int n0g = ntile << 7;
  int b = n0g >> 16;
  int p0 = n0g & (HW - 1);
  int o0 = mt << 7;
  const u16* Xb = X + (size_t)b * xbatch * HW;
  int t = threadIdx.x;
  int lane = t & 63, wv = t >> 6;
  int rb = (wv & 1) << 6, cb = (wv >> 1) << 6;
  int qd = lane >> 4, ln = lane & 15;
  f32x4 acc[4][4] = {};
  for (int c0 = 0; c0 < K; c0 += 32) {
#pragma unroll
    for (int it = 0; it < 2; ++it) {
      int tt = t + it * 256;
      int row = tt >> 2, ch = tt & 3;
      const float* wsrc = Wt + (size_t)(o0 + row) * K + c0 + ch * 8;
      uint4 pk;
      pk.x = (u32)f2bf(wsrc[0]) | ((u32)f2bf(wsrc[1]) << 16);
      pk.y = (u32)f2bf(wsrc[2]) | ((u32)f2bf(wsrc[3]) << 16);
      pk.z = (u32)f2bf(wsrc[4]) | ((u32)f2bf(wsrc[5]) << 16);
      pk.w = (u32)f2bf(wsrc[6]) | ((u32)f2bf(wsrc[7]) << 16);
      *(uint4*)&As[ch][row][0] = pk;
    }
    {
      int pp = (t & 63) << 1;
      int kc = t >> 6;
      const u16* src = Xb + (size_t)(c0 + kc * 8) * HW + p0 + pp;
      uint4 e, o;
      gatherB(src, e, o);
      *(uint4*)&Bs[kc][pp][0] = e;
      *(uint4*)&Bs[kc][pp + 1][0] = o;
    }
    __syncthreads();
    bf16x8 af[4], bfv[4];
#pragma unroll
    for (int i = 0; i < 4; ++i) {
      af[i] = *(const bf16x8*)&As[qd][rb + i * 16 + ln][0];
      bfv[i] = *(const bf16x8*)&Bs[qd][cb + i * 16 + ln][0];
    }
#pragma unroll
    for (int i = 0; i < 4; ++i)
#pragma unroll
      for (int j = 0; j < 4; ++j)
        acc[i][j] = __builtin_amdgcn_mfma_f32_16x16x32_bf16(af[i], bfv[j],
                                                            acc[i][j], 0, 0, 0);
    __syncthreads();
  }
  size_t ybase = (size_t)b * M * HW;
#pragma unroll
  for (int i = 0; i < 4; ++i) {
    int obase = o0 + rb + i * 16 + qd * 4;
#pragma unroll
    for (int j = 0; j < 4; ++j) {
      int p = p0 + cb + j * 16 + ln;
#pragma unroll
      for (int rr = 0; rr < 4; ++rr) {
        int o = obase + rr;
        size_t idx = ybase + (size_t)o * HW + p;
        float v = acc[i][j][rr];
        float r = AUXF32 ? ((const float*)aux)[idx]
                         : bf2f((u32)((const u16*)aux)[idx]);
        v = r + v * scale[o];
        if (OUTF32) ((float*)Yv)[idx] = v;
        else        ((u16*)Yv)[idx] = f2bf(v);
      }
    }
  }
}

// ------- fused LN2(over 256 ch) + v-multiply + conv1x1 GEMM (wp1 path) ------
__global__ __launch_bounds__(256, 2)
void lngemm_k(const u16* __restrict__ Wbf, const u16* __restrict__ X,
              u16* __restrict__ Y, const float* __restrict__ aux,
              const float* __restrict__ scale, const float* __restrict__ gw,
              const float* __restrict__ gb)
{
  __shared__ __align__(16) u16 At[32][128][8];   // full-K attn tile, 64 KB
  __shared__ __align__(16) u16 As[4][128][8];    // weight chunk, 8 KB
  __shared__ float stm[128], str[128];           // per-pixel mean / rstd
  int n0g = blockIdx.x << 7;
  int b = n0g >> 16;
  int p0 = n0g & (HW - 1);
  const u16* Xb = X + (size_t)b * 768 * HW;
  int t = threadIdx.x;
  int lane = t & 63, wv = t >> 6;
  int rb = (wv & 1) << 6, cb = (wv >> 1) << 6;
  int qd = lane >> 4, ln = lane & 15;
#pragma unroll
  for (int it = 0; it < 8; ++it) {
    int kc = (t >> 6) + it * 4;
    int pp = (t & 63) << 1;
    const u16* src = Xb + (size_t)(kc * 8) * HW + p0 + pp;
    uint4 e, o;
    gatherB(src, e, o);
    *(uint4*)&At[kc][pp][0] = e;
    *(uint4*)&At[kc][pp + 1][0] = o;
  }
  __syncthreads();
  if (t < 128) {
    float s0 = 0.f, q0 = 0.f;
    for (int cg = 0; cg < 128; ++cg) {
      u32 u = *(const u32*)&At[cg >> 2][t][(cg & 3) << 1];
      float a = bf2f(u & 0xffffu);
      s0 += a; q0 += a * a;
      float d = bf2f(u >> 16);
      s0 += d; q0 += d * d;
    }
    const float inv = 1.0f / 256.0f;
    float m0 = s0 * inv;
    stm[t] = m0;
    str[t] = rsqrtf(fmaxf(q0 * inv - m0 * m0, 0.f) + 1e-6f);
  }
  __syncthreads();
  f32x4 acc[4][4] = {};
  for (int c0 = 0; c0 < 256; c0 += 32) {
    {
      const uint4* wsrc = (const uint4*)(Wbf + (size_t)(c0 >> 5) * 4096);
      ((uint4*)As)[t] = wsrc[t];
      ((uint4*)As)[t + 256] = wsrc[t + 256];
    }
    {
      int kcg = (c0 >> 3) + (t >> 6);
      int pp = (t & 63) << 1;
      const u16* vsrc = Xb + (size_t)(512 + kcg * 8) * HW + p0 + pp;
      uint4 ve, vo;
      gatherB(vsrc, ve, vo);
      float w8[8], b8[8];
#pragma unroll
      for (int j = 0; j < 8; ++j) {
        w8[j] = gw[kcg * 8 + j];
        b8[j] = gb[kcg * 8 + j];
      }
      float m0 = stm[pp], r0 = str[pp];
      float m1 = stm[pp + 1], r1 = str[pp + 1];
      uint4 e = *(const uint4*)&At[kcg][pp][0];
      uint4 o = *(const uint4*)&At[kcg][pp + 1][0];
      const u32* ew = (const u32*)&e;
      const u32* ow = (const u32*)&o;
      const u32* vew = (const u32*)&ve;
      const u32* vow = (const u32*)&vo;
      u32 re[4], ro[4];
#pragma unroll
      for (int j = 0; j < 4; ++j) {
        float a0 = ((bf2f(ew[j] & 0xffffu) - m0) * r0 * w8[2 * j] + b8[2 * j]) *
                   bf2f(vew[j] & 0xffffu);
        float a1 = ((bf2f(ew[j] >> 16) - m0) * r0 * w8[2 * j + 1] + b8[2 * j + 1]) *
                   bf2f(vew[j] >> 16);
        re[j] = (u32)f2bf(a0) | ((u32)f2bf(a1) << 16);
        float d0 = ((bf2f(ow[j] & 0xffffu) - m1) * r1 * w8[2 * j] + b8[2 * j]) *
                   bf2f(vow[j] & 0xffffu);
        float d1 = ((bf2f(ow[j] >> 16) - m1) * r1 * w8[2 * j + 1] + b8[2 * j + 1]) *
                   bf2f(vow[j] >> 16);
        ro[j] = (u32)f2bf(d0) | ((u32)f2bf(d1) << 16);
      }
      *(uint4*)&At[kcg][pp][0] = *(const uint4*)re;
      *(uint4*)&At[kcg][pp + 1][0] = *(const uint4*)ro;
    }
    __syncthreads();
    bf16x8 af[4], bfv[4];
    int kb = c0 >> 3;
#pragma unroll
    for (int i = 0; i < 4; ++i) {
      af[i] = *(const bf16x8*)&As[qd][rb + i * 16 + ln][0];
      bfv[i] = *(const bf16x8*)&At[kb + qd][cb + i * 16 + ln][0];
    }
#pragma unroll
    for (int i = 0; i < 4; ++i)
#pragma unroll
      for (int j = 0; j < 4; ++j)
        acc[i][j] = __builtin_amdgcn_mfma_f32_16x16x32_bf16(af[i], bfv[j],
                                                            acc[i][j], 0, 0, 0);
    __syncthreads();
  }
  size_t ybase = (size_t)b * 128 * HW;
#pragma unroll
  for (int i = 0; i < 4; ++i) {
    int obase = rb + i * 16 + qd * 4;
#pragma unroll
    for (int j = 0; j < 4; ++j) {
      int p = p0 + cb + j * 16 + ln;
#pragma unroll
      for (int rr = 0; rr < 4; ++rr) {
        int o = obase + rr;
        size_t idx = ybase + (size_t)o * HW + p;
        float v = acc[i][j][rr];
        float r = aux[idx];
        Y[idx] = f2bf(r + v * scale[o]);
      }
    }
  }
}

// ------- folded conv1x1 GEMM, K=128, pre-converted bf16 weights -------------
template <int EPI>
__global__ __launch_bounds__(256, 2)
void gemmf_k(const u16* __restrict__ Wbf, const u16* __restrict__ X,
             u16* __restrict__ Y, const float* __restrict__ bias,
             int MT, int xbatch)
{
  __shared__ __align__(16) u16 Bs[16][128][8];   // full-K B tile, 32 KB
  __shared__ __align__(16) u16 As[16][128][8];   // full-K A tile, 32 KB
  int n0g = blockIdx.x << 7;
  int b = n0g >> 16;
  int p0 = n0g & (HW - 1);
  const u16* Xb = X + (size_t)b * xbatch * HW;
  int t = threadIdx.x;
  int lane = t & 63, wv = t >> 6;
  int rb = (wv & 1) << 6, cb = (wv >> 1) << 6;
  int qd = lane >> 4, ln = lane & 15;
#pragma unroll
  for (int it = 0; it < 4; ++it) {
    int tt = t + it * 256;
    int pp = (tt & 63) << 1;
    int kc = tt >> 6;
    const u16* src = Xb + (size_t)(kc * 8) * HW + p0 + pp;
    uint4 e, o;
    gatherB(src, e, o);
    *(uint4*)&Bs[kc][pp][0] = e;
    *(uint4*)&Bs[kc][pp + 1][0] = o;
  }
  int M = MT << 7;
  size_t ybase = (size_t)b * M * HW;
  for (int mt = 0; mt < MT; ++mt) {
    __syncthreads();   // prior tile's MFMA reads done (mt=0: B writes done)
    {
      const uint4* wsrc = (const uint4*)(Wbf + (size_t)mt * 16384);
#pragma unroll
      for (int it = 0; it < 8; ++it)
        ((uint4*)As)[t + it * 256] = wsrc[t + it * 256];
    }
    __syncthreads();
    f32x4 acc[4][4] = {};
#pragma unroll
    for (int s = 0; s < 4; ++s) {
      bf16x8 af[4], bfv[4];
#pragma unroll
      for (int i = 0; i < 4; ++i) {
        af[i] = *(const bf16x8*)&As[s * 4 + qd][rb + i * 16 + ln][0];
        bfv[i] = *(const bf16x8*)&Bs[s * 4 + qd][cb + i * 16 + ln][0];
      }
#pragma unroll
      for (int i = 0; i < 4; ++i)
#pragma unroll
        for (int j = 0; j < 4; ++j)
          acc[i][j] = __builtin_amdgcn_mfma_f32_16x16x32_bf16(af[i], bfv[j],
                                                              acc[i][j], 0, 0, 0);
    }
    int o0 = mt << 7;
#pragma unroll
    for (int i = 0; i < 4; ++i) {
      int obase = o0 + rb + i * 16 + qd * 4;
#pragma unroll
      for (int j = 0; j < 4; ++j) {
        int p = p0 + cb + j * 16 + ln;
#pragma unroll
        for (int rr = 0; rr < 4; ++rr) {
          int o = obase + rr;
          float v = acc[i][j][rr];
          if (EPI == 1) v += bias[o];
          Y[ybase + (size_t)o * HW + p] = f2bf(v);
        }
      }
    }
  }
}

// ------- fused LN3 + folded conv1x1 GEMM (wh2 path, K=128, bias) ------------
__global__ __launch_bounds__(256, 2)
void lngemmf_k(const u16* __restrict__ Wbf, const u16* __restrict__ X,
               u16* __restrict__ Y, const float* __restrict__ bias,
               const float* __restrict__ gw, const float* __restrict__ gb,
               int MT, int xbatch)
{
  __shared__ __align__(16) u16 Bs[16][128][8];   // full-K B tile, 32 KB
  __shared__ __align__(16) u16 As[16][128][8];   // full-K A tile, 32 KB
  __shared__ float stm[128], str[128];
  int n0g = blockIdx.x << 7;
  int b = n0g >> 16;
  int p0 = n0g & (HW - 1);
  const u16* Xb = X + (size_t)b * xbatch * HW;
  int t = threadIdx.x;
  int lane = t & 63, wv = t >> 6;
  int rb = (wv & 1) << 6, cb = (wv >> 1) << 6;
  int qd = lane >> 4, ln = lane & 15;
#pragma unroll
  for (int it = 0; it < 4; ++it) {
    int tt = t + it * 256;
    int pp = (tt & 63) << 1;
    int kc = tt >> 6;
    const u16* src = Xb + (size_t)(kc * 8) * HW + p0 + pp;
    uint4 e, o;
    gatherB(src, e, o);
    *(uint4*)&Bs[kc][pp][0] = e;
    *(uint4*)&Bs[kc][pp + 1][0] = o;
  }
  __syncthreads();
  if (t < 128) {
    float s = 0.f, q = 0.f;
    for (int kc = 0; kc < 16; ++kc) {
      float r8[8];
      unpack8(*(const uint4*)&Bs[kc][t][0], r8);
#pragma unroll
      for (int j = 0; j < 8; ++j) {
        float a = r8[j];
        s += a; q += a * a;
      }
    }
    const float inv = 1.0f / 128.0f;
    float m = s * inv;
    stm[t] = m;
    str[t] = rsqrtf(fmaxf(q * inv - m * m, 0.f) + 1e-6f);
  }
  __syncthreads();
  {
    int pp = (t & 63) << 1;
    float m0 = stm[pp], r0 = str[pp];
    float m1 = stm[pp + 1], r1 = str[pp + 1];
#pragma unroll
    for (int mth = 0; mth < 4; ++mth) {
      int kc = (t >> 6) + mth * 4;
      float w8[8], b8[8];
#pragma unroll
      for (int j = 0; j < 8; ++j) {
        w8[j] = gw[kc * 8 + j];
        b8[j] = gb[kc * 8 + j];
      }
      float e8[8], o8[8];
      unpack8(*(const uint4*)&Bs[kc][pp][0], e8);
      unpack8(*(const uint4*)&Bs[kc][pp + 1][0], o8);
      uint4 pe, po;
      u32* pew = (u32*)&pe;
      u32* pow = (u32*)&po;
#pragma unroll
      for (int j = 0; j < 4; ++j) {
        float a0 = (e8[2 * j] - m0) * r0 * w8[2 * j] + b8[2 * j];
        float a1 = (e8[2 * j + 1] - m0) * r0 * w8[2 * j + 1] + b8[2 * j + 1];
        pew[j] = (u32)f2bf(a0) | ((u32)f2bf(a1) << 16);
        float d0 = (o8[2 * j] - m1) * r1 * w8[2 * j] + b8[2 * j];
        float d1 = (o8[2 * j + 1] - m1) * r1 * w8[2 * j + 1] + b8[2 * j + 1];
        pow[j] = (u32)f2bf(d0) | ((u32)f2bf(d1) << 16);
      }
      *(uint4*)&Bs[kc][pp][0] = pe;
      *(uint4*)&Bs[kc][pp + 1][0] = po;
    }
  }
  int M = MT << 7;
  size_t ybase = (size_t)b * M * HW;
  for (int mt = 0; mt < MT; ++mt) {
    __syncthreads();
    {
      const uint4* wsrc = (const uint4*)(Wbf + (size_t)mt * 16384);
#pragma unroll
      for (int it = 0; it < 8; ++it)
        ((uint4*)As)[t + it * 256] = wsrc[t + it * 256];
    }
    __syncthreads();
    f32x4 acc[4][4] = {};
#pragma unroll
    for (int s = 0; s < 4; ++s) {
      bf16x8 af[4], bfv[4];
#pragma unroll
      for (int i = 0; i < 4; ++i) {
        af[i] = *(const bf16x8*)&As[s * 4 + qd][rb + i * 16 + ln][0];
        bfv[i] = *(const bf16x8*)&Bs[s * 4 + qd][cb + i * 16 + ln][0];
      }
#pragma unroll
      for (int i = 0; i < 4; ++i)
#pragma unroll
        for (int j = 0; j < 4; ++j)
          acc[i][j] = __builtin_amdgcn_mfma_f32_16x16x32_bf16(af[i], bfv[j],
                                                              acc[i][j], 0, 0, 0);
    }
    int o0 = mt << 7;
#pragma unroll
    for (int i = 0; i < 4; ++i) {
      int obase = o0 + rb + i * 16 + qd * 4;
#pragma unroll
      for (int j = 0; j < 4; ++j) {
        int p = p0 + cb + j * 16 + ln;
#pragma unroll
        for (int rr = 0; rr < 4; ++rr) {
          int o = obase + rr;
          Y[ybase + (size_t)o * HW + p] = f2bf(acc[i][j][rr] + bias[o]);
        }
      }
    }
  }
}

// ---------------- depthwise 3x3, SAME zero pad, IN-PLACE (bf16 data) --------
// v4: v1 structure (full 128 KB channel, 1536 blocks — v2/v3 restructures
// both regressed) + per-thread ROW REUSE: thread t owns 8 CONSECUTIVE rows
// h=(t>>5)*8+k, so r1,r2 of step k become r0,r1 of step k+1. LDS row reads
// per thread: 24 -> 10 b128 (+ halo u16 48 -> 20), unpack VALU ~-60%.
// In-place safety unchanged: LDS holds pristine channel, writes go to global.
__device__ __forceinline__ void ldsrow(const u16* __restrict__ img, int h,
                                       int w0, float* r) {
  if ((unsigned)h > 255u) {
#pragma unroll
    for (int i = 0; i < 10; ++i) r[i] = 0.f;
    return;
  }
  const u16* rp = img + (h << 8) + w0;
  float c[8];
  unpack8(*(const uint4*)rp, c);
#pragma unroll
  for (int i = 0; i < 8; ++i) r[i + 1] = c[i];
  r[0] = (w0 > 0) ? bf2f((u32)rp[-1]) : 0.f;
  r[9] = (w0 < 248) ? bf2f((u32)rp[8]) : 0.f;
}

__global__ __launch_bounds__(1024)
void dwip_k(u16* __restrict__ buf, const float* __restrict__ wt, int C)
{
  __shared__ __align__(16) u16 img[65536];   // 128 KB: full channel
  int bc = blockIdx.x;                       // b*C + c
  int c = bc % C;
  size_t base = (size_t)bc << 16;
  int t = threadIdx.x;
  uint4* simg = (uint4*)img;
  const uint4* gsrc = (const uint4*)(buf + base);
#pragma unroll
  for (int it = 0; it < 8; ++it)
    simg[it * 1024 + t] = gsrc[it * 1024 + t];
  float wg[9];
#pragma unroll
  for (int i = 0; i < 9; ++i) wg[i] = wt[c * 9 + i];
  __syncthreads();
  uint4* gdst = (uint4*)(buf + base);
  int col = t & 31;
  int w0 = col << 3;
  int h0 = (t >> 5) << 3;                    // 8-row strip base
  float r0[10], r1[10], r2[10];
  ldsrow(img, h0 - 1, w0, r0);               // h0==0 -> zeros
  ldsrow(img, h0,     w0, r1);
#pragma unroll
  for (int k = 0; k < 8; ++k) {
    int h = h0 + k;
    ldsrow(img, h + 1, w0, r2);              // h==255 -> zeros
    float o[8];
#pragma unroll
    for (int j = 0; j < 8; ++j) {
      float s = 0.f;
#pragma unroll
      for (int dx = 0; dx < 3; ++dx)
        s += r0[j + dx] * wg[dx] + r1[j + dx] * wg[3 + dx] +
             r2[j + dx] * wg[6 + dx];
      o[j] = s;
    }
    uint4 pk;
    pk.x = (u32)f2bf(o[0]) | ((u32)f2bf(o[1]) << 16);
    pk.y = (u32)f2bf(o[2]) | ((u32)f2bf(o[3]) << 16);
    pk.z = (u32)f2bf(o[4]) | ((u32)f2bf(o[5]) << 16);
    pk.w = (u32)f2bf(o[6]) | ((u32)f2bf(o[7]) << 16);
    gdst[(h << 5) + col] = pk;               // global write; LDS stays pristine
#pragma unroll
    for (int i = 0; i < 10; ++i) { r0[i] = r1[i]; r1[i] = r2[i]; }
  }
}

// ---------------- fused depthwise-3x3 + gate product (FFN tail) -------------
// v2: same row-reuse as dwip v4 — thread owns 4 consecutive output rows;
// identical mapping in both passes keeps the o1 gate pairs aligned.
__device__ __forceinline__ void ldsrow2(const u16* __restrict__ img, int lr,
                                        int w0, float* r) {
  const u16* rp = img + (lr << 8) + w0;
  float c[8];
  unpack8(*(const uint4*)rp, c);
#pragma unroll
  for (int i = 0; i < 8; ++i) r[i + 1] = c[i];
  r[0] = (w0 > 0) ? bf2f((u32)rp[-1]) : 0.f;
  r[9] = (w0 < 248) ? bf2f((u32)rp[8]) : 0.f;
}

__global__ __launch_bounds__(1024)
void dwfuse_k(const u16* __restrict__ h4, const float* __restrict__ wt,
              u16* __restrict__ pr)
{
  __shared__ __align__(16) u16 img[33280];   // 130 rows x 256, 66.5 KB
  int bx = blockIdx.x;
  int b = bx >> 8;
  int c = (bx >> 1) & 127;
  int half = bx & 1;
  int h0 = half << 7;
  int t = threadIdx.x;
  float o1[32];
  size_t obase = ((size_t)((b << 7) + c) << 16);
  int col = t & 31;
  int w0 = col << 3;
  int l0 = (t >> 5) << 2;                    // 4-row strip base (0..124)
#pragma unroll
  for (int pass = 0; pass < 2; ++pass) {
    int ch = c + pass * 128;
    size_t gbase = (size_t)((b << 8) + ch) << 16;
    __syncthreads();             // prior pass conv reads complete
    for (int idx = t; idx < 4160; idx += 1024) {
      int lr = idx >> 5, cl = idx & 31;
      int gh = h0 - 1 + lr;
      uint4 v = {0, 0, 0, 0};
      if ((unsigned)gh < 256u)
        v = *(const uint4*)(h4 + gbase + ((size_t)gh << 8) + cl * 8);
      *(uint4*)&img[(lr << 8) + cl * 8] = v;
    }
    float wg[9];
#pragma unroll
    for (int i = 0; i < 9; ++i) wg[i] = wt[ch * 9 + i];
    __syncthreads();
    float r0[10], r1[10], r2[10];
    ldsrow2(img, l0,     w0, r0);            // global row h0+l0-1
    ldsrow2(img, l0 + 1, w0, r1);
#pragma unroll
    for (int k = 0; k < 4; ++k) {
      int lrr = l0 + k;                      // output row h0+lrr
      ldsrow2(img, lrr + 2, w0, r2);
      float o[8];
#pragma unroll
      for (int j = 0; j < 8; ++j) {
        float s = 0.f;
#pragma unroll
        for (int dx = 0; dx < 3; ++dx)
          s += r0[j + dx] * wg[dx] + r1[j + dx] * wg[3 + dx] +
               r2[j + dx] * wg[6 + dx];
        o[j] = s;
      }
      if (pass == 0) {
#pragma unroll
        for (int j = 0; j < 8; ++j) o1[k * 8 + j] = o[j];
      } else {
        uint4 pk;
        pk.x = (u32)f2bf(o1[k*8+0] * o[0]) | ((u32)f2bf(o1[k*8+1] * o[1]) << 16);
        pk.y = (u32)f2bf(o1[k*8+2] * o[2]) | ((u32)f2bf(o1[k*8+3] * o[3]) << 16);
        pk.z = (u32)f2bf(o1[k*8+4] * o[4]) | ((u32)f2bf(o1[k*8+5] * o[5]) << 16);
        pk.w = (u32)f2bf(o1[k*8+6] * o[6]) | ((u32)f2bf(o1[k*8+7] * o[7]) << 16);
        *(uint4*)(pr + obase + ((size_t)(h0 + lrr) << 8) + w0) = pk;
      }
#pragma unroll
      for (int i = 0; i < 10; ++i) { r0[i] = r1[i]; r1[i] = r2[i]; }
    }
  }
}

// ---------------- patch-FFT attention = 8x8 circular conv per patch/channel -
__global__ __launch_bounds__(256)
void attn_k(u16* __restrict__ qkv)
{
  int wv = threadIdx.x >> 6, lane = threadIdx.x & 63;
  int task = blockIdx.x * 4 + wv;       // 8192 tasks: b(2) x c(256) x strip(16)
  int b = task >> 12;
  int c = (task >> 4) & 255;
  int strip = task & 15;
  int pr = lane >> 5, pw = lane & 31;
  int row = (strip << 4) + (pr << 3);   // patch top row
  size_t qbase = ((size_t)(b * 768 + c) << 16) + ((size_t)row << 8) + pw * 8;
  size_t kbase = qbase + ((size_t)256 << 16);
  u32 qp[8][4];
  u32 ku[8][4];
#pragma unroll
  for (int i = 0; i < 8; ++i) {
    uint4 qv = *(const uint4*)(qkv + qbase + (i << 8));
    uint4 kv = *(const uint4*)(qkv + kbase + (i << 8));
    qp[i][0] = qv.x; qp[i][1] = qv.y; qp[i][2] = qv.z; qp[i][3] = qv.w;
    ku[i][0] = kv.x; ku[i][1] = kv.y; ku[i][2] = kv.z; ku[i][3] = kv.w;
  }
  // pk[r][n] = pack(lo=k[r][n], hi=k[r][(n-1)&7])
  u32 pk[8][8];
#pragma unroll
  for (int r = 0; r < 8; ++r)
#pragma unroll
    for (int n = 0; n < 8; ++n) {
      if (n & 1) {
        u32 x = ku[r][n >> 1];
        pk[r][n] = (x >> 16) | (x << 16);
      } else {
        pk[r][n] = (ku[r][n >> 1] & 0xffffu) |
                   (ku[r][((n + 7) & 7) >> 1] & 0xffff0000u);
      }
    }
#pragma unroll
  for (int m = 0; m < 8; ++m) {
    float a[8] = {};
#pragma unroll
    for (int i = 0; i < 8; ++i) {
      const int r = (m - i) & 7;
#pragma unroll
      for (int t = 0; t < 4; ++t) {
        const u32 q = qp[i][t];
#pragma unroll
        for (int n = 0; n < 8; ++n)
          a[n] = dot2bf(q, pk[r][(n - 2 * t) & 7], a[n]);
      }
    }
    uint4 pko;
    pko.x = (u32)f2bf(a[0]) | ((u32)f2bf(a[1]) << 16);
    pko.y = (u32)f2bf(a[2]) | ((u32)f2bf(a[3]) << 16);
    pko.z = (u32)f2bf(a[4]) | ((u32)f2bf(a[5]) << 16);
    pko.w = (u32)f2bf(a[6]) | ((u32)f2bf(a[7]) << 16);
    *(uint4*)(qkv + qbase + (m << 8)) = pko;
  }
}

extern "C" void kernel_launch(void* const* d_in, const int* in_sizes, int n_in,
                              void* d_out, int out_size, void* d_ws, size_t ws_size,
                              hipStream_t stream)
{
  (void)in_sizes; (void)n_in; (void)out_size; (void)ws_size;
  const float* x    = (const float*)d_in[0];
  const float* n1w  = (const float*)d_in[1];
  const float* n1b  = (const float*)d_in[2];
  const float* wh1  = (const float*)d_in[3];
  const float* wdw1 = (const float*)d_in[4];
  const float* n2w  = (const float*)d_in[5];
  const float* n2b  = (const float*)d_in[6];
  const float* wp1  = (const float*)d_in[7];
  const float* n3w  = (const float*)d_in[8];
  const float* n3b  = (const float*)d_in[9];
  const float* wh2  = (const float*)d_in[10];
  const float* bh2  = (const float*)d_in[11];
  const float* wdw2 = (const float*)d_in[12];
  const float* wp2  = (const float*)d_in[13];
  const float* sc1  = (const float*)d_in[14];
  const float* sc2  = (const float*)d_in[15];
  float* out = (float*)d_out;
  u16* ws = (u16*)d_ws;

  // workspace (u16 elems), peak ~235 MB:
  //   A = ws          : (2,768,HW)  hidden -> qkv -> attn (raw, in q-slot)
  //                     later: h4 [16.7M,50.3M) | pr [0,16.7M)
  //   B = ws + 100.7M : (2,128,HW)  hln -> xmid (bf16)
  // d_out doubles as bf16-weight scratch (dead until final kernel overwrites):
  //   S0=wh1bf [0,98304) | S1=wp1bf [98304,131072) | S2=wh2bf [131072,163840)
  u16* A = ws;
  u16* B = ws + 100663296;
  u16* h4 = A + 16777216;
  u16* pr = A;
  u16* S = (u16*)d_out;

  wprep_k<<<640, 256, 0, stream>>>(wh1, wp1, wh2, S);                        // bf16 weights
  ln1_k<<<1024, 256, 0, stream>>>(x, n1w, n1b, B);                           // hln (1-pass)
  gemmf_k<0><<<1024, 256, 0, stream>>>(S, B, A, nullptr, 6, 128);            // hidden
  dwip_k<<<1536, 1024, 0, stream>>>(A, wdw1, 768);                           // qkv
  attn_k<<<2048, 256, 0, stream>>>(A);                                       // attn -> q-slot
  lngemm_k<<<1024, 256, 0, stream>>>(S + 98304, A, B, x, sc1, n2w, n2b);     // LN2+v*+wp1 -> B
  lngemmf_k<<<1024, 256, 0, stream>>>(S + 131072, B, h4, bh2, n3w, n3b, 2, 128); // LN3+wh2 -> h4
  dwfuse_k<<<512, 1024, 0, stream>>>(h4, wdw2, pr);                          // pr = g1*g2
  gemm_k<0,1><<<1024, 256, 0, stream>>>(wp2, pr, out, B, sc2, 128, 128, 128);
}